// Round 18
// baseline (523.542 us; speedup 1.0000x reference)
//
#include <hip/hip_runtime.h>
#include <hip/hip_bf16.h>

#define MC 4096
#define DD 128
#define NHH 4
#define DH 32
#define FFD 256
#define NS 3
#define NSPLIT 4
#define PLEN 1024

typedef __attribute__((ext_vector_type(8))) short short8_t;
typedef __attribute__((ext_vector_type(4))) float f32x4;

__device__ __forceinline__ int getM(int s, const int* M0, const int* M1, const int* M2) {
    return (s == 0) ? *M0 : (s == 1) ? *M1 : *M2;
}

__device__ __forceinline__ unsigned short f2bf(float f) {
    unsigned int u = __float_as_uint(f);
    u += 0x7FFFu + ((u >> 16) & 1u);   // RNE
    return (unsigned short)(u >> 16);
}

__device__ __forceinline__ short8_t pack8(float4 a, float4 b) {
    short8_t r;
    r[0] = (short)f2bf(a.x); r[1] = (short)f2bf(a.y);
    r[2] = (short)f2bf(a.z); r[3] = (short)f2bf(a.w);
    r[4] = (short)f2bf(b.x); r[5] = (short)f2bf(b.y);
    r[6] = (short)f2bf(b.z); r[7] = (short)f2bf(b.w);
    return r;
}

__device__ __forceinline__ f32x4 max4(f32x4 a, f32x4 b) {
    f32x4 r;
    r[0] = fmaxf(a[0], b[0]); r[1] = fmaxf(a[1], b[1]);
    r[2] = fmaxf(a[2], b[2]); r[3] = fmaxf(a[3], b[3]);
    return r;
}
__device__ __forceinline__ f32x4 shflx4(f32x4 a, int m) {
    f32x4 r;
    r[0] = __shfl_xor(a[0], m); r[1] = __shfl_xor(a[1], m);
    r[2] = __shfl_xor(a[2], m); r[3] = __shfl_xor(a[3], m);
    return r;
}
__device__ __forceinline__ f32x4 exp4(f32x4 a) {
    f32x4 r;
    r[0] = __expf(a[0]); r[1] = __expf(a[1]);
    r[2] = __expf(a[2]); r[3] = __expf(a[3]);
    return r;
}

// ---------------- parent maps + scale-0 histogram in one pass ----------------
__global__ void k_parent(const int* __restrict__ inv0, const int* __restrict__ inv1,
                         const int* __restrict__ inv2,
                         int* __restrict__ parent10, int* __restrict__ parent21,
                         int* __restrict__ cnt, int N)
{
    int n = blockIdx.x * blockDim.x + threadIdx.x;
    if (n >= N) return;
    int i0 = inv0[n];
    parent10[i0] = inv1[n];   // duplicate writes all agree (grids nest)
    parent21[inv1[n]] = inv2[n];
    atomicAdd(&cnt[i0], 1);
}

// ---------------- exclusive scan over MC=4096 bins, single block 1024 thr ----------------
__global__ void k_scan(const int* __restrict__ cnt, int* __restrict__ offs)
{
    __shared__ int arr[1024];
    int tid = threadIdx.x;
    int base = tid * 4;
    int c0 = cnt[base], c1 = cnt[base + 1], c2 = cnt[base + 2], c3 = cnt[base + 3];
    int tot = c0 + c1 + c2 + c3;
    arr[tid] = tot;
    __syncthreads();
    for (int off = 1; off < 1024; off <<= 1) {
        int v = (tid >= off) ? arr[tid - off] : 0;
        __syncthreads();
        arr[tid] += v;
        __syncthreads();
    }
    int excl = arr[tid] - tot;
    offs[base] = excl;
    offs[base + 1] = excl + c0;
    offs[base + 2] = excl + c0 + c1;
    offs[base + 3] = excl + c0 + c1 + c2;
}

// ---------------- placement: order[] groups particles by voxel ----------------
__global__ void k_place(const int* __restrict__ inv0, const int* __restrict__ offs,
                        int* __restrict__ fill, int* __restrict__ order, int N)
{
    int n = blockIdx.x * blockDim.x + threadIdx.x;
    if (n >= N) return;
    int i0 = inv0[n];
    int pos = offs[i0] + atomicAdd(&fill[i0], 1);
    order[pos] = n;
}

// ---------------- pooled sums: float4/thread, 8 row-slots, 2x unrolled ----------------
__global__ __launch_bounds__(256) void k_pool(const float* __restrict__ h,
                                              const int* __restrict__ order,
                                              const int* __restrict__ offs,
                                              const int* __restrict__ cnt,
                                              float* __restrict__ sum0, float* __restrict__ cnt0,
                                              const int* __restrict__ M0)
{
    int v = blockIdx.x;
    if (v >= *M0) return;
    int beg = offs[v], len = cnt[v];
    int tid = threadIdx.x;
    int dg = tid & 31;          // dim group: dims dg*4 .. dg*4+3
    int rs = tid >> 5;          // row slot 0..7
    const int* op = order + beg;

    float ax = 0.f, ay = 0.f, az = 0.f, aw = 0.f;
    int j = rs;
    for (; j + 8 < len; j += 16) {
        int r0 = op[j];
        int r1 = op[j + 8];
        float4 a = *(const float4*)(h + (size_t)r0 * DD + dg * 4);
        float4 b = *(const float4*)(h + (size_t)r1 * DD + dg * 4);
        ax += a.x + b.x; ay += a.y + b.y; az += a.z + b.z; aw += a.w + b.w;
    }
    if (j < len) {
        int r0 = op[j];
        float4 a = *(const float4*)(h + (size_t)r0 * DD + dg * 4);
        ax += a.x; ay += a.y; az += a.z; aw += a.w;
    }

    __shared__ __align__(16) float red[8][DD];
    *(float4*)&red[rs][dg * 4] = make_float4(ax, ay, az, aw);
    __syncthreads();
    if (tid < 32) {
        float4 t0 = *(const float4*)&red[0][tid * 4];
        float4 t1 = *(const float4*)&red[1][tid * 4];
        float4 t2 = *(const float4*)&red[2][tid * 4];
        float4 t3 = *(const float4*)&red[3][tid * 4];
        float4 t4 = *(const float4*)&red[4][tid * 4];
        float4 t5 = *(const float4*)&red[5][tid * 4];
        float4 t6 = *(const float4*)&red[6][tid * 4];
        float4 t7 = *(const float4*)&red[7][tid * 4];
        float4 r;
        r.x = ((t0.x + t1.x) + (t2.x + t3.x)) + ((t4.x + t5.x) + (t6.x + t7.x));
        r.y = ((t0.y + t1.y) + (t2.y + t3.y)) + ((t4.y + t5.y) + (t6.y + t7.y));
        r.z = ((t0.z + t1.z) + (t2.z + t3.z)) + ((t4.z + t5.z) + (t6.z + t7.z));
        r.w = ((t0.w + t1.w) + (t2.w + t3.w)) + ((t4.w + t5.w) + (t6.w + t7.w));
        *(float4*)(sum0 + (size_t)v * DD + tid * 4) = r;
        if (tid == 0) cnt0[v] = (float)len;
    }
}

// ---------------- both rollups in ONE pass from sum0 (R17: -1 launch, shorter chain) ----------------
__global__ void k_rollup_both(const float* __restrict__ sum0, const float* __restrict__ cnt0,
                              const int* __restrict__ parent10, const int* __restrict__ parent21,
                              float* __restrict__ sum1, float* __restrict__ cnt1,
                              float* __restrict__ sum2, float* __restrict__ cnt2,
                              const int* __restrict__ M0)
{
    int idx = blockIdx.x * blockDim.x + threadIdx.x;   // < MC*DD
    int v = idx >> 7, d = idx & 127;
    if (v >= *M0) return;
    int p1 = parent10[v];
    int p2 = parent21[p1];
    float val = sum0[idx];
    atomicAdd(&sum1[(size_t)p1 * DD + d], val);
    atomicAdd(&sum2[(size_t)p2 * DD + d], val);
    if (d == 0) {
        float c = cnt0[v];
        atomicAdd(&cnt1[p1], c);
        atomicAdd(&cnt2[p2], c);
    }
}

// ---------------- divide by clamped counts + b0frag (fused, R17) ----------------
__global__ void k_finalize(float* __restrict__ macro, const float* __restrict__ counts,
                           const float* __restrict__ Wf, unsigned short* __restrict__ b0f,
                           const int* M0, const int* M1, const int* M2)
{
    int idx = blockIdx.x * blockDim.x + threadIdx.x;
    if (idx < NS * MC * DD) {
        int s = idx / (MC * DD);
        int r = (idx >> 7) & (MC - 1);
        if (r >= getM(s, M0, M1, M2)) return;
        float c = counts[s * MC + r];
        macro[idx] /= fmaxf(c, 1.0f);
    } else {
        int e = idx - NS * MC * DD;        // < 16384: b0frag
        int j = e & 7, l = (e >> 3) & 63, kt = (e >> 9) & 3, nt = e >> 11;
        int d = nt * 16 + (l & 15);
        int k = kt * 32 + (l >> 4) * 8 + j;
        b0f[e] = f2bf(Wf[(size_t)d * (4 * DD) + k]);
    }
}

// ---------------- qkv = macro @ Wqkv[s].T + bqkv[s], 8 rows/block ----------------
__global__ void k_qkv(const float* __restrict__ macro, const float* __restrict__ Wqkv,
                      const float* __restrict__ bqkv, float* __restrict__ qkv,
                      const int* M0, const int* M1, const int* M2)
{
    int s = blockIdx.y;
    int Ms = getM(s, M0, M1, M2);
    int row0 = blockIdx.x * 8;
    if (row0 >= Ms) return;
    __shared__ __align__(16) float mac[8][DD];
    int tid = threadIdx.x;
    for (int e = tid; e < 8 * DD; e += 256) {
        int r = e >> 7, d = e & 127;
        int row = row0 + r;
        mac[r][d] = (row < Ms) ? macro[(size_t)s * MC * DD + (size_t)row * DD + d] : 0.0f;
    }
    __syncthreads();
    for (int j = tid; j < 3 * DD; j += 256) {
        const float* w = Wqkv + ((size_t)s * 3 * DD + j) * DD;
        float b = bqkv[s * 3 * DD + j];
        float acc[8];
#pragma unroll
        for (int r = 0; r < 8; ++r) acc[r] = b;
        for (int k = 0; k < DD; k += 4) {
            float4 w4 = *(const float4*)(w + k);
#pragma unroll
            for (int r = 0; r < 8; ++r) {
                float4 m4 = *(const float4*)&mac[r][k];
                acc[r] += w4.x * m4.x + w4.y * m4.y + w4.z * m4.z + w4.w * m4.w;
            }
        }
        for (int r = 0; r < 8; ++r) {
            int row = row0 + r;
            if (row < Ms) qkv[((size_t)s * MC + row) * (3 * DD) + j] = acc[r];
        }
    }
}

// ---------------- MFMA flash attention partials, DOUBLE-BUFFERED staging ----------------
__global__ __launch_bounds__(256) void k_attn_part(const float* __restrict__ qkv,
                                                   float* __restrict__ part_o,
                                                   float* __restrict__ part_ml,
                                                   const int* M0, const int* M1, const int* M2)
{
    int z = blockIdx.z;
    int s = z / NSPLIT, part = z % NSPLIT;
    int head = blockIdx.y;
    int Ms = getM(s, M0, M1, M2);
    int q0 = blockIdx.x * 64;
    if (q0 >= Ms) return;
    int kstart = part * PLEN;
    if (kstart >= Ms) return;
    int kend = kstart + PLEN; if (kend > Ms) kend = Ms;

    __shared__ __align__(16) unsigned short kf[2][4][64][8];
    __shared__ __align__(16) unsigned short vf[2][2][2][64][8];
    __shared__ __align__(16) unsigned short pf[4][16][80];

    int tid = threadIdx.x;
    int wave = tid >> 6, lane = tid & 63;
    int c = lane & 15, g = lane >> 4;

    const float* base = qkv + (size_t)s * MC * 3 * DD;
    const float* Qb = base + head * DH;
    const float* Kb = base + DD + head * DH;
    const float* Vb = base + 2 * DD + head * DH;

    short8_t qfrag = {0,0,0,0,0,0,0,0};
    {
        int qr = q0 + wave * 16 + c;
        if (qr < Ms) {
            const float* qp = Qb + (size_t)qr * 3 * DD + g * 8;
            qfrag = pack8(*(const float4*)qp, *(const float4*)(qp + 4));
        }
    }

    f32x4 o0 = {0.f, 0.f, 0.f, 0.f}, o1 = {0.f, 0.f, 0.f, 0.f};
    f32x4 mreg = {-1e30f, -1e30f, -1e30f, -1e30f};
    f32x4 lreg = {0.f, 0.f, 0.f, 0.f};
    const float scale = 0.1767766952966369f;  // 1/sqrt(32)

    int sko = tid >> 2, sg = tid & 3;
    int s_nt = sko >> 4;
    int s_l  = (sko & 15) | (sg << 4);
    int s_ks = sko >> 5, s_kk = sko & 31;
    int s_j  = s_kk & 7, s_hi = (s_kk >> 3) & 3;
    int s_vnt = sg >> 1, s_db = (sg & 1) * 8;

    auto STAGE = [&](int buf, int kb) {
        {
            int key = kb + sko;
            short8_t kv = {0,0,0,0,0,0,0,0};
            if (key < kend) {
                const float* kr = Kb + (size_t)key * 3 * DD + sg * 8;
                kv = pack8(*(const float4*)kr, *(const float4*)(kr + 4));
            }
            *(short8_t*)&kf[buf][s_nt][s_l][0] = kv;
        }
        {
            int key = kb + sko;
            float4 a = make_float4(0.f, 0.f, 0.f, 0.f);
            float4 b = make_float4(0.f, 0.f, 0.f, 0.f);
            if (key < kend) {
                const float* vr = Vb + (size_t)key * 3 * DD + sg * 8;
                a = *(const float4*)vr;
                b = *(const float4*)(vr + 4);
            }
            unsigned short* vslot = &vf[buf][s_ks][s_vnt][0][0];
            vslot[((s_db + 0) | (s_hi << 4)) * 8 + s_j] = f2bf(a.x);
            vslot[((s_db + 1) | (s_hi << 4)) * 8 + s_j] = f2bf(a.y);
            vslot[((s_db + 2) | (s_hi << 4)) * 8 + s_j] = f2bf(a.z);
            vslot[((s_db + 3) | (s_hi << 4)) * 8 + s_j] = f2bf(a.w);
            vslot[((s_db + 4) | (s_hi << 4)) * 8 + s_j] = f2bf(b.x);
            vslot[((s_db + 5) | (s_hi << 4)) * 8 + s_j] = f2bf(b.y);
            vslot[((s_db + 6) | (s_hi << 4)) * 8 + s_j] = f2bf(b.z);
            vslot[((s_db + 7) | (s_hi << 4)) * 8 + s_j] = f2bf(b.w);
        }
    };

    STAGE(0, kstart);
    __syncthreads();
    int cur = 0;

    for (int kb = kstart; kb < kend; kb += 64) {
        if (kb + 64 < kend) STAGE(cur ^ 1, kb + 64);

        f32x4 zero = {0.f, 0.f, 0.f, 0.f};
        short8_t kf0 = *(const short8_t*)&kf[cur][0][lane][0];
        short8_t kf1 = *(const short8_t*)&kf[cur][1][lane][0];
        short8_t kf2 = *(const short8_t*)&kf[cur][2][lane][0];
        short8_t kf3 = *(const short8_t*)&kf[cur][3][lane][0];
        f32x4 a0 = __builtin_amdgcn_mfma_f32_16x16x32_bf16(qfrag, kf0, zero, 0, 0, 0);
        f32x4 a1 = __builtin_amdgcn_mfma_f32_16x16x32_bf16(qfrag, kf1, zero, 0, 0, 0);
        f32x4 a2 = __builtin_amdgcn_mfma_f32_16x16x32_bf16(qfrag, kf2, zero, 0, 0, 0);
        f32x4 a3 = __builtin_amdgcn_mfma_f32_16x16x32_bf16(qfrag, kf3, zero, 0, 0, 0);

        f32x4 neg = {-1e30f, -1e30f, -1e30f, -1e30f};
        a0 = (kb +  0 + c < kend) ? a0 * scale : neg;
        a1 = (kb + 16 + c < kend) ? a1 * scale : neg;
        a2 = (kb + 32 + c < kend) ? a2 * scale : neg;
        a3 = (kb + 48 + c < kend) ? a3 * scale : neg;

        f32x4 rmax = max4(max4(a0, a1), max4(a2, a3));
        rmax = max4(rmax, shflx4(rmax, 1));
        rmax = max4(rmax, shflx4(rmax, 2));
        rmax = max4(rmax, shflx4(rmax, 4));
        rmax = max4(rmax, shflx4(rmax, 8));
        f32x4 mnew = max4(mreg, rmax);
        f32x4 alpha = exp4(mreg - mnew);
        mreg = mnew;
        lreg = lreg * alpha;
        o0 = o0 * alpha;
        o1 = o1 * alpha;

        a0 = exp4(a0 - mnew);
        a1 = exp4(a1 - mnew);
        a2 = exp4(a2 - mnew);
        a3 = exp4(a3 - mnew);
        f32x4 rsum = (a0 + a1) + (a2 + a3);
        rsum = rsum + shflx4(rsum, 1);
        rsum = rsum + shflx4(rsum, 2);
        rsum = rsum + shflx4(rsum, 4);
        rsum = rsum + shflx4(rsum, 8);
        lreg = lreg + rsum;

        {
            unsigned short* prow = &pf[wave][0][0];
            int rb = g * 4;
            prow[(rb + 0) * 80 +  0 + c] = f2bf(a0[0]);
            prow[(rb + 1) * 80 +  0 + c] = f2bf(a0[1]);
            prow[(rb + 2) * 80 +  0 + c] = f2bf(a0[2]);
            prow[(rb + 3) * 80 +  0 + c] = f2bf(a0[3]);
            prow[(rb + 0) * 80 + 16 + c] = f2bf(a1[0]);
            prow[(rb + 1) * 80 + 16 + c] = f2bf(a1[1]);
            prow[(rb + 2) * 80 + 16 + c] = f2bf(a1[2]);
            prow[(rb + 3) * 80 + 16 + c] = f2bf(a1[3]);
            prow[(rb + 0) * 80 + 32 + c] = f2bf(a2[0]);
            prow[(rb + 1) * 80 + 32 + c] = f2bf(a2[1]);
            prow[(rb + 2) * 80 + 32 + c] = f2bf(a2[2]);
            prow[(rb + 3) * 80 + 32 + c] = f2bf(a2[3]);
            prow[(rb + 0) * 80 + 48 + c] = f2bf(a3[0]);
            prow[(rb + 1) * 80 + 48 + c] = f2bf(a3[1]);
            prow[(rb + 2) * 80 + 48 + c] = f2bf(a3[2]);
            prow[(rb + 3) * 80 + 48 + c] = f2bf(a3[3]);
        }

        {
            short8_t p0 = *(const short8_t*)&pf[wave][c][ 0 + g * 8];
            short8_t v00 = *(const short8_t*)&vf[cur][0][0][lane][0];
            short8_t v01 = *(const short8_t*)&vf[cur][0][1][lane][0];
            o0 = __builtin_amdgcn_mfma_f32_16x16x32_bf16(p0, v00, o0, 0, 0, 0);
            o1 = __builtin_amdgcn_mfma_f32_16x16x32_bf16(p0, v01, o1, 0, 0, 0);
            short8_t p1 = *(const short8_t*)&pf[wave][c][32 + g * 8];
            short8_t v10 = *(const short8_t*)&vf[cur][1][0][lane][0];
            short8_t v11 = *(const short8_t*)&vf[cur][1][1][lane][0];
            o0 = __builtin_amdgcn_mfma_f32_16x16x32_bf16(p1, v10, o0, 0, 0, 0);
            o1 = __builtin_amdgcn_mfma_f32_16x16x32_bf16(p1, v11, o1, 0, 0, 0);
        }

        __syncthreads();
        cur ^= 1;
    }

    int rec = ((s * NHH + head) * 64 + blockIdx.x) * NSPLIT + part;
    float* po = part_o + (size_t)rec * 2048;
    int qb = wave * 16 + g * 4;
    po[(qb + 0) * 32 + c] = o0[0];
    po[(qb + 1) * 32 + c] = o0[1];
    po[(qb + 2) * 32 + c] = o0[2];
    po[(qb + 3) * 32 + c] = o0[3];
    po[(qb + 0) * 32 + 16 + c] = o1[0];
    po[(qb + 1) * 32 + 16 + c] = o1[1];
    po[(qb + 2) * 32 + 16 + c] = o1[2];
    po[(qb + 3) * 32 + 16 + c] = o1[3];
    if (c == 0) {
        part_ml[rec * 128 + qb + 0] = mreg[0];
        part_ml[rec * 128 + qb + 1] = mreg[1];
        part_ml[rec * 128 + qb + 2] = mreg[2];
        part_ml[rec * 128 + qb + 3] = mreg[3];
        part_ml[rec * 128 + 64 + qb + 0] = lreg[0];
        part_ml[rec * 128 + 64 + qb + 1] = lreg[1];
        part_ml[rec * 128 + 64 + qb + 2] = lreg[2];
        part_ml[rec * 128 + 64 + qb + 3] = lreg[3];
    }
}

// ---------------- merge split-K partials ----------------
__global__ void k_attn_comb(const float* __restrict__ part_o, const float* __restrict__ part_ml,
                            float* __restrict__ attno,
                            const int* M0, const int* M1, const int* M2)
{
    int s = blockIdx.z, head = blockIdx.y;
    int Ms = getM(s, M0, M1, M2);
    int q0 = blockIdx.x * 64;
    if (q0 >= Ms) return;
    int tid = threadIdx.x;
    int qi = tid >> 2, sub = tid & 3;
    int nparts = (Ms + PLEN - 1) / PLEN;
    if (nparts > NSPLIT) nparts = NSPLIT;
    int recbase = ((s * NHH + head) * 64 + blockIdx.x) * NSPLIT;

    float m = -1e30f;
    for (int p = 0; p < nparts; ++p)
        m = fmaxf(m, part_ml[(recbase + p) * 128 + qi]);
    float L = 0.f;
    float4 A0 = {0,0,0,0}, A1 = {0,0,0,0};
    for (int p = 0; p < nparts; ++p) {
        float mp = part_ml[(recbase + p) * 128 + qi];
        float lp = part_ml[(recbase + p) * 128 + 64 + qi];
        float w = __expf(mp - m);
        L += lp * w;
        const float* po = part_o + (size_t)(recbase + p) * 2048;
        float4 a = *(const float4*)(po + qi * 32 + sub * 4);
        float4 b = *(const float4*)(po + qi * 32 + (sub + 4) * 4);
        A0.x += a.x * w; A0.y += a.y * w; A0.z += a.z * w; A0.w += a.w * w;
        A1.x += b.x * w; A1.y += b.y * w; A1.z += b.z * w; A1.w += b.w * w;
    }
    if (q0 + qi < Ms) {
        float inv = 1.0f / fmaxf(L, 1e-30f);
        size_t orow = ((size_t)s * MC + q0 + qi) * DD + head * DH;
        float4 r0 = make_float4(A0.x * inv, A0.y * inv, A0.z * inv, A0.w * inv);
        float4 r1 = make_float4(A1.x * inv, A1.y * inv, A1.z * inv, A1.w * inv);
        *(float4*)(attno + orow + sub * 4) = r0;
        *(float4*)(attno + orow + (sub + 4) * 4) = r1;
    }
}

// ---------------- fused LN1+FFN+LN2+yproj, 8 ROWS PER BLOCK ----------------
__global__ __launch_bounds__(256) void k_layer(const float* __restrict__ macro,
                                               const float* __restrict__ attno,
                                               const float* __restrict__ Wo, const float* __restrict__ bo,
                                               const float* __restrict__ ln1s, const float* __restrict__ ln1b,
                                               const float* __restrict__ W1, const float* __restrict__ b1,
                                               const float* __restrict__ W2, const float* __restrict__ b2,
                                               const float* __restrict__ ln2s, const float* __restrict__ ln2b,
                                               const float* __restrict__ Wf,
                                               float* __restrict__ y,
                                               const int* M0, const int* M1, const int* M2)
{
    int s = blockIdx.y;
    int Ms = getM(s, M0, M1, M2);
    int row0 = blockIdx.x * 8;
    if (row0 >= Ms) return;
    __shared__ __align__(16) float os8[8][DD];   // attno rows -> later x2 rows
    __shared__ __align__(16) float xr8[8][DD];   // x1 rows
    __shared__ __align__(16) float ts8[8][FFD];  // ffn hidden
    __shared__ float mv[8][2];
    int tid = threadIdx.x;  // 256
    int rr = tid >> 5, tt = tid & 31;   // (row, 32-lane slot) for stage/LN phases

    {
        int row = row0 + rr;
        float4 v = make_float4(0.f, 0.f, 0.f, 0.f);
        if (row < Ms) v = *(const float4*)(attno + ((size_t)s * MC + row) * DD + tt * 4);
        *(float4*)&os8[rr][tt * 4] = v;
    }
    __syncthreads();

    float acc[8];

    // ---- Wo proj + residual -> xr8 (pre-LN) ----
    if (tid < DD) {
        const float* w = Wo + ((size_t)s * DD + tid) * DD;
        float b = bo[s * DD + tid];
#pragma unroll
        for (int r = 0; r < 8; ++r) acc[r] = b;
        for (int k = 0; k < DD; k += 4) {
            float4 w4 = *(const float4*)(w + k);
#pragma unroll
            for (int r = 0; r < 8; ++r) {
                float4 m4 = *(const float4*)&os8[r][k];
                acc[r] += w4.x * m4.x + w4.y * m4.y + w4.z * m4.z + w4.w * m4.w;
            }
        }
#pragma unroll
        for (int r = 0; r < 8; ++r) {
            int row = row0 + r;
            float res = (row < Ms) ? macro[((size_t)s * MC + row) * DD + tid] : 0.f;
            xr8[r][tid] = acc[r] + res;
        }
    }
    __syncthreads();

    // ---- LN1 reduce (32 lanes per row) + apply ----
    {
        float4 v = *(const float4*)&xr8[rr][tt * 4];
        float su = v.x + v.y + v.z + v.w;
        float sq = v.x * v.x + v.y * v.y + v.z * v.z + v.w * v.w;
        for (int off = 16; off >= 1; off >>= 1) { su += __shfl_xor(su, off); sq += __shfl_xor(sq, off); }
        if (tt == 0) { mv[rr][0] = su; mv[rr][1] = sq; }
    }
    __syncthreads();
    {
        float mean = mv[rr][0] * (1.0f / DD);
        float var = fmaxf(mv[rr][1] * (1.0f / DD) - mean * mean, 0.0f);
        float rstd = rsqrtf(var + 1e-5f);
        float4 v = *(const float4*)&xr8[rr][tt * 4];
        float4 gs = *(const float4*)(ln1s + s * DD + tt * 4);
        float4 gb = *(const float4*)(ln1b + s * DD + tt * 4);
        float4 o;
        o.x = (v.x - mean) * rstd * gs.x + gb.x;
        o.y = (v.y - mean) * rstd * gs.y + gb.y;
        o.z = (v.z - mean) * rstd * gs.z + gb.z;
        o.w = (v.w - mean) * rstd * gs.w + gb.w;
        *(float4*)&xr8[rr][tt * 4] = o;
    }
    __syncthreads();

    // ---- FFN t1: ts8 = relu(xr8 @ W1.T + b1), all 256 threads ----
    {
        const float* w = W1 + ((size_t)s * FFD + tid) * DD;
        float b = b1[s * FFD + tid];
#pragma unroll
        for (int r = 0; r < 8; ++r) acc[r] = b;
        for (int k = 0; k < DD; k += 4) {
            float4 w4 = *(const float4*)(w + k);
#pragma unroll
            for (int r = 0; r < 8; ++r) {
                float4 m4 = *(const float4*)&xr8[r][k];
                acc[r] += w4.x * m4.x + w4.y * m4.y + w4.z * m4.z + w4.w * m4.w;
            }
        }
#pragma unroll
        for (int r = 0; r < 8; ++r) ts8[r][tid] = fmaxf(acc[r], 0.0f);
    }
    __syncthreads();

    // ---- FFN t2 + residual -> os8 (pre-LN) ----
    if (tid < DD) {
        const float* w = W2 + ((size_t)s * DD + tid) * FFD;
        float b = b2[s * DD + tid];
#pragma unroll
        for (int r = 0; r < 8; ++r) acc[r] = b;
        for (int k = 0; k < FFD; k += 4) {
            float4 w4 = *(const float4*)(w + k);
#pragma unroll
            for (int r = 0; r < 8; ++r) {
                float4 m4 = *(const float4*)&ts8[r][k];
                acc[r] += w4.x * m4.x + w4.y * m4.y + w4.z * m4.z + w4.w * m4.w;
            }
        }
#pragma unroll
        for (int r = 0; r < 8; ++r) os8[r][tid] = acc[r] + xr8[r][tid];
    }
    __syncthreads();

    // ---- LN2 reduce + apply -> os8 ----
    {
        float4 v = *(const float4*)&os8[rr][tt * 4];
        float su = v.x + v.y + v.z + v.w;
        float sq = v.x * v.x + v.y * v.y + v.z * v.z + v.w * v.w;
        for (int off = 16; off >= 1; off >>= 1) { su += __shfl_xor(su, off); sq += __shfl_xor(sq, off); }
        if (tt == 0) { mv[rr][0] = su; mv[rr][1] = sq; }
    }
    __syncthreads();
    {
        float mean = mv[rr][0] * (1.0f / DD);
        float var = fmaxf(mv[rr][1] * (1.0f / DD) - mean * mean, 0.0f);
        float rstd = rsqrtf(var + 1e-5f);
        float4 v = *(const float4*)&os8[rr][tt * 4];
        float4 gs = *(const float4*)(ln2s + s * DD + tt * 4);
        float4 gb = *(const float4*)(ln2b + s * DD + tt * 4);
        float4 o;
        o.x = (v.x - mean) * rstd * gs.x + gb.x;
        o.y = (v.y - mean) * rstd * gs.y + gb.y;
        o.z = (v.z - mean) * rstd * gs.z + gb.z;
        o.w = (v.w - mean) * rstd * gs.w + gb.w;
        *(float4*)&os8[rr][tt * 4] = o;
    }
    __syncthreads();

    // ---- yproj ----
    if (tid < DD) {
        const float* w = Wf + (size_t)tid * (4 * DD) + (s + 1) * DD;
#pragma unroll
        for (int r = 0; r < 8; ++r) acc[r] = 0.f;
        for (int k = 0; k < DD; k += 4) {
            float4 w4 = *(const float4*)(w + k);
#pragma unroll
            for (int r = 0; r < 8; ++r) {
                float4 m4 = *(const float4*)&os8[r][k];
                acc[r] += w4.x * m4.x + w4.y * m4.y + w4.z * m4.z + w4.w * m4.w;
            }
        }
#pragma unroll
        for (int r = 0; r < 8; ++r) {
            int row = row0 + r;
            if (row < Ms) y[((size_t)s * MC + row) * DD + tid] = acc[r];
        }
    }
}

// ---------------- out = h@B0 (bf16 MFMA) + y0/y1/y2 gathers + bf (R17: no ycomb) ----------------
__global__ __launch_bounds__(256) void k_final(const float* __restrict__ h,
                                               const unsigned short* __restrict__ b0f,
                                               const float* __restrict__ y,
                                               const int* __restrict__ inv0,
                                               const int* __restrict__ inv1,
                                               const int* __restrict__ inv2,
                                               const float* __restrict__ bf,
                                               float* __restrict__ out, int N)
{
    int tid = threadIdx.x;
    int wave = tid >> 6, lane = tid & 63;
    int c = lane & 15, g = lane >> 4;
    const float* y0 = y;
    const float* y1 = y + (size_t)MC * DD;
    const float* y2 = y + (size_t)2 * MC * DD;

    int ntasks = (N + 15) >> 4;
    int pair = blockIdx.x * 4 + wave;
    int taskA = pair * 2;
    if (taskA >= ntasks) return;
    int taskB = taskA + 1;

    int pA = taskA * 16 + c;
    int pB = taskB * 16 + c;
    bool okA = (pA < N);
    bool okB = (taskB < ntasks) && (pB < N);

    short8_t hA0 = {0,0,0,0,0,0,0,0}, hA1 = hA0, hA2 = hA0, hA3 = hA0;
    short8_t hB0 = hA0, hB1 = hA0, hB2 = hA0, hB3 = hA0;
    int iA0 = 0, iA1 = 0, iA2 = 0, iB0 = 0, iB1 = 0, iB2 = 0;
    if (okA) {
        const float* hr = h + (size_t)pA * DD + g * 8;
        hA0 = pack8(*(const float4*)(hr +  0), *(const float4*)(hr +  4));
        hA1 = pack8(*(const float4*)(hr + 32), *(const float4*)(hr + 36));
        hA2 = pack8(*(const float4*)(hr + 64), *(const float4*)(hr + 68));
        hA3 = pack8(*(const float4*)(hr + 96), *(const float4*)(hr + 100));
        iA0 = inv0[pA]; iA1 = inv1[pA]; iA2 = inv2[pA];
    }
    if (okB) {
        const float* hr = h + (size_t)pB * DD + g * 8;
        hB0 = pack8(*(const float4*)(hr +  0), *(const float4*)(hr +  4));
        hB1 = pack8(*(const float4*)(hr + 32), *(const float4*)(hr + 36));
        hB2 = pack8(*(const float4*)(hr + 64), *(const float4*)(hr + 68));
        hB3 = pack8(*(const float4*)(hr + 96), *(const float4*)(hr + 100));
        iB0 = inv0[pB]; iB1 = inv1[pB]; iB2 = inv2[pB];
    }
    const float* yA0 = y0 + (size_t)iA0 * DD;
    const float* yA1 = y1 + (size_t)iA1 * DD;
    const float* yA2 = y2 + (size_t)iA2 * DD;
    const float* yB0 = y0 + (size_t)iB0 * DD;
    const float* yB1 = y1 + (size_t)iB1 * DD;
    const float* yB2 = y2 + (size_t)iB2 * DD;

#pragma unroll
    for (int ntp = 0; ntp < 4; ++ntp) {
        int nt0 = ntp * 2, nt1 = ntp * 2 + 1;
        f32x4 aA0 = {0.f, 0.f, 0.f, 0.f}, aA1 = {0.f, 0.f, 0.f, 0.f};
        f32x4 aB0 = {0.f, 0.f, 0.f, 0.f}, aB1 = {0.f, 0.f, 0.f, 0.f};
        {
            short8_t w00 = *(const short8_t*)(b0f + (size_t)((nt0 * 4 + 0) * 64 + lane) * 8);
            aA0 = __builtin_amdgcn_mfma_f32_16x16x32_bf16(w00, hA0, aA0, 0, 0, 0);
            aB0 = __builtin_amdgcn_mfma_f32_16x16x32_bf16(w00, hB0, aB0, 0, 0, 0);
            short8_t w10 = *(const short8_t*)(b0f + (size_t)((nt1 * 4 + 0) * 64 + lane) * 8);
            aA1 = __builtin_amdgcn_mfma_f32_16x16x32_bf16(w10, hA0, aA1, 0, 0, 0);
            aB1 = __builtin_amdgcn_mfma_f32_16x16x32_bf16(w10, hB0, aB1, 0, 0, 0);
            short8_t w01 = *(const short8_t*)(b0f + (size_t)((nt0 * 4 + 1) * 64 + lane) * 8);
            aA0 = __builtin_amdgcn_mfma_f32_16x16x32_bf16(w01, hA1, aA0, 0, 0, 0);
            aB0 = __builtin_amdgcn_mfma_f32_16x16x32_bf16(w01, hB1, aB0, 0, 0, 0);
            short8_t w11 = *(const short8_t*)(b0f + (size_t)((nt1 * 4 + 1) * 64 + lane) * 8);
            aA1 = __builtin_amdgcn_mfma_f32_16x16x32_bf16(w11, hA1, aA1, 0, 0, 0);
            aB1 = __builtin_amdgcn_mfma_f32_16x16x32_bf16(w11, hB1, aB1, 0, 0, 0);
            short8_t w02 = *(const short8_t*)(b0f + (size_t)((nt0 * 4 + 2) * 64 + lane) * 8);
            aA0 = __builtin_amdgcn_mfma_f32_16x16x32_bf16(w02, hA2, aA0, 0, 0, 0);
            aB0 = __builtin_amdgcn_mfma_f32_16x16x32_bf16(w02, hB2, aB0, 0, 0, 0);
            short8_t w12 = *(const short8_t*)(b0f + (size_t)((nt1 * 4 + 2) * 64 + lane) * 8);
            aA1 = __builtin_amdgcn_mfma_f32_16x16x32_bf16(w12, hA2, aA1, 0, 0, 0);
            aB1 = __builtin_amdgcn_mfma_f32_16x16x32_bf16(w12, hB2, aB1, 0, 0, 0);
            short8_t w03 = *(const short8_t*)(b0f + (size_t)((nt0 * 4 + 3) * 64 + lane) * 8);
            aA0 = __builtin_amdgcn_mfma_f32_16x16x32_bf16(w03, hA3, aA0, 0, 0, 0);
            aB0 = __builtin_amdgcn_mfma_f32_16x16x32_bf16(w03, hB3, aB0, 0, 0, 0);
            short8_t w13 = *(const short8_t*)(b0f + (size_t)((nt1 * 4 + 3) * 64 + lane) * 8);
            aA1 = __builtin_amdgcn_mfma_f32_16x16x32_bf16(w13, hA3, aA1, 0, 0, 0);
            aB1 = __builtin_amdgcn_mfma_f32_16x16x32_bf16(w13, hB3, aB1, 0, 0, 0);
        }
        int d0 = nt0 * 16 + g * 4;
        int d1 = d0 + 16;
        if (okA) {
            float4 gA00 = *(const float4*)(yA0 + d0);
            float4 gA10 = *(const float4*)(yA1 + d0);
            float4 gA20 = *(const float4*)(yA2 + d0);
            float4 b40 = *(const float4*)(bf + d0);
            float4 gA01 = *(const float4*)(yA0 + d1);
            float4 gA11 = *(const float4*)(yA1 + d1);
            float4 gA21 = *(const float4*)(yA2 + d1);
            float4 b41 = *(const float4*)(bf + d1);
            float4 r0, r1;
            r0.x = aA0[0] + gA00.x + gA10.x + gA20.x + b40.x;
            r0.y = aA0[1] + gA00.y + gA10.y + gA20.y + b40.y;
            r0.z = aA0[2] + gA00.z + gA10.z + gA20.z + b40.z;
            r0.w = aA0[3] + gA00.w + gA10.w + gA20.w + b40.w;
            r1.x = aA1[0] + gA01.x + gA11.x + gA21.x + b41.x;
            r1.y = aA1[1] + gA01.y + gA11.y + gA21.y + b41.y;
            r1.z = aA1[2] + gA01.z + gA11.z + gA21.z + b41.z;
            r1.w = aA1[3] + gA01.w + gA11.w + gA21.w + b41.w;
            *(float4*)(out + (size_t)pA * DD + d0) = r0;
            *(float4*)(out + (size_t)pA * DD + d1) = r1;
        }
        if (okB) {
            float4 gB00 = *(const float4*)(yB0 + d0);
            float4 gB10 = *(const float4*)(yB1 + d0);
            float4 gB20 = *(const float4*)(yB2 + d0);
            float4 b40 = *(const float4*)(bf + d0);
            float4 gB01 = *(const float4*)(yB0 + d1);
            float4 gB11 = *(const float4*)(yB1 + d1);
            float4 gB21 = *(const float4*)(yB2 + d1);
            float4 b41 = *(const float4*)(bf + d1);
            float4 r0, r1;
            r0.x = aB0[0] + gB00.x + gB10.x + gB20.x + b40.x;
            r0.y = aB0[1] + gB00.y + gB10.y + gB20.y + b40.y;
            r0.z = aB0[2] + gB00.z + gB10.z + gB20.z + b40.z;
            r0.w = aB0[3] + gB00.w + gB10.w + gB20.w + b40.w;
            r1.x = aB1[0] + gB01.x + gB11.x + gB21.x + b41.x;
            r1.y = aB1[1] + gB01.y + gB11.y + gB21.y + b41.y;
            r1.z = aB1[2] + gB01.z + gB11.z + gB21.z + b41.z;
            r1.w = aB1[3] + gB01.w + gB11.w + gB21.w + b41.w;
            *(float4*)(out + (size_t)pB * DD + d0) = r0;
            *(float4*)(out + (size_t)pB * DD + d1) = r1;
        }
    }
}

extern "C" void kernel_launch(void* const* d_in, const int* in_sizes, int n_in,
                              void* d_out, int out_size, void* d_ws, size_t ws_size,
                              hipStream_t stream) {
    (void)n_in; (void)out_size; (void)ws_size;
    const float* h   = (const float*)d_in[0];
    const int* inv0  = (const int*)d_in[2];
    const int* inv1  = (const int*)d_in[3];
    const int* inv2  = (const int*)d_in[4];
    const int* M0    = (const int*)d_in[5];
    const int* M1    = (const int*)d_in[6];
    const int* M2    = (const int*)d_in[7];
    const float* Wqkv = (const float*)d_in[8];
    const float* bqkv = (const float*)d_in[9];
    const float* Wo   = (const float*)d_in[10];
    const float* bo   = (const float*)d_in[11];
    const float* ln1s = (const float*)d_in[12];
    const float* ln1b = (const float*)d_in[13];
    const float* W1   = (const float*)d_in[14];
    const float* b1   = (const float*)d_in[15];
    const float* W2   = (const float*)d_in[16];
    const float* b2   = (const float*)d_in[17];
    const float* ln2s = (const float*)d_in[18];
    const float* ln2b = (const float*)d_in[19];
    const float* Wf   = (const float*)d_in[20];
    const float* bf   = (const float*)d_in[21];
    int N = in_sizes[0] / DD;

    float* ws      = (float*)d_ws;
    float* macro   = ws;                                    // NS*MC*DD
    float* counts  = macro + (size_t)NS * MC * DD;          // NS*MC
    float* qkvb    = counts + (size_t)NS * MC;              // NS*MC*3*DD
    float* attno   = qkvb + (size_t)NS * MC * 3 * DD;       // NS*MC*DD
    float* yb      = attno + (size_t)NS * MC * DD;          // NS*MC*DD
    float* b0f_f   = yb + (size_t)NS * MC * DD;             // DD*DD floats of space (b0f uses half)
    unsigned short* b0f = (unsigned short*)b0f_f;
    float* part_o  = b0f_f + (size_t)DD * DD;               // NS*NHH*64*NSPLIT*2048
    float* part_ml = part_o + (size_t)NS * NHH * 64 * NSPLIT * 2048;  // NS*NHH*64*NSPLIT*128
    int* ip        = (int*)(part_ml + (size_t)NS * NHH * 64 * NSPLIT * 128);
    int* parent10  = ip;                // MC
    int* parent21  = parent10 + MC;     // 512
    int* cnt_i     = parent21 + 512;    // MC
    int* fill      = cnt_i + MC;        // MC
    int* offs      = fill + MC;         // MC
    int* order     = offs + MC;         // N

    float* sum0 = macro;
    float* sum1 = macro + (size_t)1 * MC * DD;
    float* sum2 = macro + (size_t)2 * MC * DD;
    float* cnt0 = counts;
    float* cnt1 = counts + MC;
    float* cnt2 = counts + 2 * MC;

    hipMemsetAsync(macro, 0, ((size_t)NS * MC * DD + NS * MC) * sizeof(float), stream);
    hipMemsetAsync(cnt_i, 0, (size_t)2 * MC * sizeof(int), stream);

    int nb = (N + 255) / 256;
    k_parent<<<nb, 256, 0, stream>>>(inv0, inv1, inv2, parent10, parent21, cnt_i, N);
    k_scan<<<1, 1024, 0, stream>>>(cnt_i, offs);
    k_place<<<nb, 256, 0, stream>>>(inv0, offs, fill, order, N);
    k_pool<<<MC, 256, 0, stream>>>(h, order, offs, cnt_i, sum0, cnt0, M0);
    k_rollup_both<<<(MC * DD) / 256, 256, 0, stream>>>(sum0, cnt0, parent10, parent21,
                                                       sum1, cnt1, sum2, cnt2, M0);
    k_finalize<<<(NS * MC * DD + DD * DD) / 256, 256, 0, stream>>>(macro, counts, Wf, b0f, M0, M1, M2);
    k_qkv<<<dim3(MC / 8, NS), 256, 0, stream>>>(macro, Wqkv, bqkv, qkvb, M0, M1, M2);
    k_attn_part<<<dim3(MC / 64, NHH, NS * NSPLIT), 256, 0, stream>>>(qkvb, part_o, part_ml, M0, M1, M2);
    k_attn_comb<<<dim3(MC / 64, NHH, NS), 256, 0, stream>>>(part_o, part_ml, attno, M0, M1, M2);
    k_layer<<<dim3(MC / 8, NS), 256, 0, stream>>>(macro, attno, Wo, bo, ln1s, ln1b,
                                                  W1, b1, W2, b2, ln2s, ln2b, Wf, yb, M0, M1, M2);
    int ntasks = (N + 15) >> 4;
    int npairs = (ntasks + 1) / 2;
    k_final<<<(npairs + 3) / 4, 256, 0, stream>>>(h, b0f, yb, inv0, inv1, inv2, bf, (float*)d_out, N);
}

// Round 19
// 478.533 us; speedup vs baseline: 1.0941x; 1.0941x over previous
//
#include <hip/hip_runtime.h>
#include <hip/hip_bf16.h>

#define MC 4096
#define DD 128
#define NHH 4
#define DH 32
#define FFD 256
#define NS 3
#define NSPLIT 4
#define PLEN 1024

typedef __attribute__((ext_vector_type(8))) short short8_t;
typedef __attribute__((ext_vector_type(4))) float f32x4;

__device__ __forceinline__ int getM(int s, const int* M0, const int* M1, const int* M2) {
    return (s == 0) ? *M0 : (s == 1) ? *M1 : *M2;
}

__device__ __forceinline__ unsigned short f2bf(float f) {
    unsigned int u = __float_as_uint(f);
    u += 0x7FFFu + ((u >> 16) & 1u);   // RNE
    return (unsigned short)(u >> 16);
}

__device__ __forceinline__ short8_t pack8(float4 a, float4 b) {
    short8_t r;
    r[0] = (short)f2bf(a.x); r[1] = (short)f2bf(a.y);
    r[2] = (short)f2bf(a.z); r[3] = (short)f2bf(a.w);
    r[4] = (short)f2bf(b.x); r[5] = (short)f2bf(b.y);
    r[6] = (short)f2bf(b.z); r[7] = (short)f2bf(b.w);
    return r;
}

__device__ __forceinline__ f32x4 max4(f32x4 a, f32x4 b) {
    f32x4 r;
    r[0] = fmaxf(a[0], b[0]); r[1] = fmaxf(a[1], b[1]);
    r[2] = fmaxf(a[2], b[2]); r[3] = fmaxf(a[3], b[3]);
    return r;
}
__device__ __forceinline__ f32x4 shflx4(f32x4 a, int m) {
    f32x4 r;
    r[0] = __shfl_xor(a[0], m); r[1] = __shfl_xor(a[1], m);
    r[2] = __shfl_xor(a[2], m); r[3] = __shfl_xor(a[3], m);
    return r;
}
__device__ __forceinline__ f32x4 exp4(f32x4 a) {
    f32x4 r;
    r[0] = __expf(a[0]); r[1] = __expf(a[1]);
    r[2] = __expf(a[2]); r[3] = __expf(a[3]);
    return r;
}

// ---------------- parent maps + scale-0 histogram in one pass ----------------
__global__ void k_parent(const int* __restrict__ inv0, const int* __restrict__ inv1,
                         const int* __restrict__ inv2,
                         int* __restrict__ parent10, int* __restrict__ parent21,
                         int* __restrict__ cnt, int N)
{
    int n = blockIdx.x * blockDim.x + threadIdx.x;
    if (n >= N) return;
    int i0 = inv0[n];
    parent10[i0] = inv1[n];   // duplicate writes all agree (grids nest)
    parent21[inv1[n]] = inv2[n];
    atomicAdd(&cnt[i0], 1);
}

// ---------------- exclusive scan over MC=4096 bins, single block 1024 thr ----------------
__global__ void k_scan(const int* __restrict__ cnt, int* __restrict__ offs)
{
    __shared__ int arr[1024];
    int tid = threadIdx.x;
    int base = tid * 4;
    int c0 = cnt[base], c1 = cnt[base + 1], c2 = cnt[base + 2], c3 = cnt[base + 3];
    int tot = c0 + c1 + c2 + c3;
    arr[tid] = tot;
    __syncthreads();
    for (int off = 1; off < 1024; off <<= 1) {
        int v = (tid >= off) ? arr[tid - off] : 0;
        __syncthreads();
        arr[tid] += v;
        __syncthreads();
    }
    int excl = arr[tid] - tot;
    offs[base] = excl;
    offs[base + 1] = excl + c0;
    offs[base + 2] = excl + c0 + c1;
    offs[base + 3] = excl + c0 + c1 + c2;
}

// ---------------- placement: order[] groups particles by voxel ----------------
__global__ void k_place(const int* __restrict__ inv0, const int* __restrict__ offs,
                        int* __restrict__ fill, int* __restrict__ order, int N)
{
    int n = blockIdx.x * blockDim.x + threadIdx.x;
    if (n >= N) return;
    int i0 = inv0[n];
    int pos = offs[i0] + atomicAdd(&fill[i0], 1);
    order[pos] = n;
}

// ---------------- pooled sums: float4/thread, 8 row-slots, 2x unrolled ----------------
__global__ __launch_bounds__(256) void k_pool(const float* __restrict__ h,
                                              const int* __restrict__ order,
                                              const int* __restrict__ offs,
                                              const int* __restrict__ cnt,
                                              float* __restrict__ sum0, float* __restrict__ cnt0,
                                              const int* __restrict__ M0)
{
    int v = blockIdx.x;
    if (v >= *M0) return;
    int beg = offs[v], len = cnt[v];
    int tid = threadIdx.x;
    int dg = tid & 31;          // dim group: dims dg*4 .. dg*4+3
    int rs = tid >> 5;          // row slot 0..7
    const int* op = order + beg;

    float ax = 0.f, ay = 0.f, az = 0.f, aw = 0.f;
    int j = rs;
    for (; j + 8 < len; j += 16) {
        int r0 = op[j];
        int r1 = op[j + 8];
        float4 a = *(const float4*)(h + (size_t)r0 * DD + dg * 4);
        float4 b = *(const float4*)(h + (size_t)r1 * DD + dg * 4);
        ax += a.x + b.x; ay += a.y + b.y; az += a.z + b.z; aw += a.w + b.w;
    }
    if (j < len) {
        int r0 = op[j];
        float4 a = *(const float4*)(h + (size_t)r0 * DD + dg * 4);
        ax += a.x; ay += a.y; az += a.z; aw += a.w;
    }

    __shared__ __align__(16) float red[8][DD];
    *(float4*)&red[rs][dg * 4] = make_float4(ax, ay, az, aw);
    __syncthreads();
    if (tid < 32) {
        float4 t0 = *(const float4*)&red[0][tid * 4];
        float4 t1 = *(const float4*)&red[1][tid * 4];
        float4 t2 = *(const float4*)&red[2][tid * 4];
        float4 t3 = *(const float4*)&red[3][tid * 4];
        float4 t4 = *(const float4*)&red[4][tid * 4];
        float4 t5 = *(const float4*)&red[5][tid * 4];
        float4 t6 = *(const float4*)&red[6][tid * 4];
        float4 t7 = *(const float4*)&red[7][tid * 4];
        float4 r;
        r.x = ((t0.x + t1.x) + (t2.x + t3.x)) + ((t4.x + t5.x) + (t6.x + t7.x));
        r.y = ((t0.y + t1.y) + (t2.y + t3.y)) + ((t4.y + t5.y) + (t6.y + t7.y));
        r.z = ((t0.z + t1.z) + (t2.z + t3.z)) + ((t4.z + t5.z) + (t6.z + t7.z));
        r.w = ((t0.w + t1.w) + (t2.w + t3.w)) + ((t4.w + t5.w) + (t6.w + t7.w));
        *(float4*)(sum0 + (size_t)v * DD + tid * 4) = r;
        if (tid == 0) cnt0[v] = (float)len;
    }
}

// ---------------- both rollups in ONE pass from sum0 ----------------
__global__ void k_rollup_both(const float* __restrict__ sum0, const float* __restrict__ cnt0,
                              const int* __restrict__ parent10, const int* __restrict__ parent21,
                              float* __restrict__ sum1, float* __restrict__ cnt1,
                              float* __restrict__ sum2, float* __restrict__ cnt2,
                              const int* __restrict__ M0)
{
    int idx = blockIdx.x * blockDim.x + threadIdx.x;   // < MC*DD
    int v = idx >> 7, d = idx & 127;
    if (v >= *M0) return;
    int p1 = parent10[v];
    int p2 = parent21[p1];
    float val = sum0[idx];
    atomicAdd(&sum1[(size_t)p1 * DD + d], val);
    atomicAdd(&sum2[(size_t)p2 * DD + d], val);
    if (d == 0) {
        float c = cnt0[v];
        atomicAdd(&cnt1[p1], c);
        atomicAdd(&cnt2[p2], c);
    }
}

// ---------------- divide by clamped counts + b0frag (fused) ----------------
__global__ void k_finalize(float* __restrict__ macro, const float* __restrict__ counts,
                           const float* __restrict__ Wf, unsigned short* __restrict__ b0f,
                           const int* M0, const int* M1, const int* M2)
{
    int idx = blockIdx.x * blockDim.x + threadIdx.x;
    if (idx < NS * MC * DD) {
        int s = idx / (MC * DD);
        int r = (idx >> 7) & (MC - 1);
        if (r >= getM(s, M0, M1, M2)) return;
        float c = counts[s * MC + r];
        macro[idx] /= fmaxf(c, 1.0f);
    } else {
        int e = idx - NS * MC * DD;        // < 16384: b0frag
        int j = e & 7, l = (e >> 3) & 63, kt = (e >> 9) & 3, nt = e >> 11;
        int d = nt * 16 + (l & 15);
        int k = kt * 32 + (l >> 4) * 8 + j;
        b0f[e] = f2bf(Wf[(size_t)d * (4 * DD) + k]);
    }
}

// ---------------- qkv = macro @ Wqkv[s].T + bqkv[s], 8 rows/block ----------------
__global__ void k_qkv(const float* __restrict__ macro, const float* __restrict__ Wqkv,
                      const float* __restrict__ bqkv, float* __restrict__ qkv,
                      const int* M0, const int* M1, const int* M2)
{
    int s = blockIdx.y;
    int Ms = getM(s, M0, M1, M2);
    int row0 = blockIdx.x * 8;
    if (row0 >= Ms) return;
    __shared__ __align__(16) float mac[8][DD];
    int tid = threadIdx.x;
    for (int e = tid; e < 8 * DD; e += 256) {
        int r = e >> 7, d = e & 127;
        int row = row0 + r;
        mac[r][d] = (row < Ms) ? macro[(size_t)s * MC * DD + (size_t)row * DD + d] : 0.0f;
    }
    __syncthreads();
    for (int j = tid; j < 3 * DD; j += 256) {
        const float* w = Wqkv + ((size_t)s * 3 * DD + j) * DD;
        float b = bqkv[s * 3 * DD + j];
        float acc[8];
#pragma unroll
        for (int r = 0; r < 8; ++r) acc[r] = b;
        for (int k = 0; k < DD; k += 4) {
            float4 w4 = *(const float4*)(w + k);
#pragma unroll
            for (int r = 0; r < 8; ++r) {
                float4 m4 = *(const float4*)&mac[r][k];
                acc[r] += w4.x * m4.x + w4.y * m4.y + w4.z * m4.z + w4.w * m4.w;
            }
        }
        for (int r = 0; r < 8; ++r) {
            int row = row0 + r;
            if (row < Ms) qkv[((size_t)s * MC + row) * (3 * DD) + j] = acc[r];
        }
    }
}

// ---------------- MFMA flash attention partials, DOUBLE-BUFFERED staging ----------------
__global__ __launch_bounds__(256) void k_attn_part(const float* __restrict__ qkv,
                                                   float* __restrict__ part_o,
                                                   float* __restrict__ part_ml,
                                                   const int* M0, const int* M1, const int* M2)
{
    int z = blockIdx.z;
    int s = z / NSPLIT, part = z % NSPLIT;
    int head = blockIdx.y;
    int Ms = getM(s, M0, M1, M2);
    int q0 = blockIdx.x * 64;
    if (q0 >= Ms) return;
    int kstart = part * PLEN;
    if (kstart >= Ms) return;
    int kend = kstart + PLEN; if (kend > Ms) kend = Ms;

    __shared__ __align__(16) unsigned short kf[2][4][64][8];
    __shared__ __align__(16) unsigned short vf[2][2][2][64][8];
    __shared__ __align__(16) unsigned short pf[4][16][80];

    int tid = threadIdx.x;
    int wave = tid >> 6, lane = tid & 63;
    int c = lane & 15, g = lane >> 4;

    const float* base = qkv + (size_t)s * MC * 3 * DD;
    const float* Qb = base + head * DH;
    const float* Kb = base + DD + head * DH;
    const float* Vb = base + 2 * DD + head * DH;

    short8_t qfrag = {0,0,0,0,0,0,0,0};
    {
        int qr = q0 + wave * 16 + c;
        if (qr < Ms) {
            const float* qp = Qb + (size_t)qr * 3 * DD + g * 8;
            qfrag = pack8(*(const float4*)qp, *(const float4*)(qp + 4));
        }
    }

    f32x4 o0 = {0.f, 0.f, 0.f, 0.f}, o1 = {0.f, 0.f, 0.f, 0.f};
    f32x4 mreg = {-1e30f, -1e30f, -1e30f, -1e30f};
    f32x4 lreg = {0.f, 0.f, 0.f, 0.f};
    const float scale = 0.1767766952966369f;  // 1/sqrt(32)

    int sko = tid >> 2, sg = tid & 3;
    int s_nt = sko >> 4;
    int s_l  = (sko & 15) | (sg << 4);
    int s_ks = sko >> 5, s_kk = sko & 31;
    int s_j  = s_kk & 7, s_hi = (s_kk >> 3) & 3;
    int s_vnt = sg >> 1, s_db = (sg & 1) * 8;

    auto STAGE = [&](int buf, int kb) {
        {
            int key = kb + sko;
            short8_t kv = {0,0,0,0,0,0,0,0};
            if (key < kend) {
                const float* kr = Kb + (size_t)key * 3 * DD + sg * 8;
                kv = pack8(*(const float4*)kr, *(const float4*)(kr + 4));
            }
            *(short8_t*)&kf[buf][s_nt][s_l][0] = kv;
        }
        {
            int key = kb + sko;
            float4 a = make_float4(0.f, 0.f, 0.f, 0.f);
            float4 b = make_float4(0.f, 0.f, 0.f, 0.f);
            if (key < kend) {
                const float* vr = Vb + (size_t)key * 3 * DD + sg * 8;
                a = *(const float4*)vr;
                b = *(const float4*)(vr + 4);
            }
            unsigned short* vslot = &vf[buf][s_ks][s_vnt][0][0];
            vslot[((s_db + 0) | (s_hi << 4)) * 8 + s_j] = f2bf(a.x);
            vslot[((s_db + 1) | (s_hi << 4)) * 8 + s_j] = f2bf(a.y);
            vslot[((s_db + 2) | (s_hi << 4)) * 8 + s_j] = f2bf(a.z);
            vslot[((s_db + 3) | (s_hi << 4)) * 8 + s_j] = f2bf(a.w);
            vslot[((s_db + 4) | (s_hi << 4)) * 8 + s_j] = f2bf(b.x);
            vslot[((s_db + 5) | (s_hi << 4)) * 8 + s_j] = f2bf(b.y);
            vslot[((s_db + 6) | (s_hi << 4)) * 8 + s_j] = f2bf(b.z);
            vslot[((s_db + 7) | (s_hi << 4)) * 8 + s_j] = f2bf(b.w);
        }
    };

    STAGE(0, kstart);
    __syncthreads();
    int cur = 0;

    for (int kb = kstart; kb < kend; kb += 64) {
        if (kb + 64 < kend) STAGE(cur ^ 1, kb + 64);

        f32x4 zero = {0.f, 0.f, 0.f, 0.f};
        short8_t kf0 = *(const short8_t*)&kf[cur][0][lane][0];
        short8_t kf1 = *(const short8_t*)&kf[cur][1][lane][0];
        short8_t kf2 = *(const short8_t*)&kf[cur][2][lane][0];
        short8_t kf3 = *(const short8_t*)&kf[cur][3][lane][0];
        f32x4 a0 = __builtin_amdgcn_mfma_f32_16x16x32_bf16(qfrag, kf0, zero, 0, 0, 0);
        f32x4 a1 = __builtin_amdgcn_mfma_f32_16x16x32_bf16(qfrag, kf1, zero, 0, 0, 0);
        f32x4 a2 = __builtin_amdgcn_mfma_f32_16x16x32_bf16(qfrag, kf2, zero, 0, 0, 0);
        f32x4 a3 = __builtin_amdgcn_mfma_f32_16x16x32_bf16(qfrag, kf3, zero, 0, 0, 0);

        f32x4 neg = {-1e30f, -1e30f, -1e30f, -1e30f};
        a0 = (kb +  0 + c < kend) ? a0 * scale : neg;
        a1 = (kb + 16 + c < kend) ? a1 * scale : neg;
        a2 = (kb + 32 + c < kend) ? a2 * scale : neg;
        a3 = (kb + 48 + c < kend) ? a3 * scale : neg;

        f32x4 rmax = max4(max4(a0, a1), max4(a2, a3));
        rmax = max4(rmax, shflx4(rmax, 1));
        rmax = max4(rmax, shflx4(rmax, 2));
        rmax = max4(rmax, shflx4(rmax, 4));
        rmax = max4(rmax, shflx4(rmax, 8));
        f32x4 mnew = max4(mreg, rmax);
        f32x4 alpha = exp4(mreg - mnew);
        mreg = mnew;
        lreg = lreg * alpha;
        o0 = o0 * alpha;
        o1 = o1 * alpha;

        a0 = exp4(a0 - mnew);
        a1 = exp4(a1 - mnew);
        a2 = exp4(a2 - mnew);
        a3 = exp4(a3 - mnew);
        f32x4 rsum = (a0 + a1) + (a2 + a3);
        rsum = rsum + shflx4(rsum, 1);
        rsum = rsum + shflx4(rsum, 2);
        rsum = rsum + shflx4(rsum, 4);
        rsum = rsum + shflx4(rsum, 8);
        lreg = lreg + rsum;

        {
            unsigned short* prow = &pf[wave][0][0];
            int rb = g * 4;
            prow[(rb + 0) * 80 +  0 + c] = f2bf(a0[0]);
            prow[(rb + 1) * 80 +  0 + c] = f2bf(a0[1]);
            prow[(rb + 2) * 80 +  0 + c] = f2bf(a0[2]);
            prow[(rb + 3) * 80 +  0 + c] = f2bf(a0[3]);
            prow[(rb + 0) * 80 + 16 + c] = f2bf(a1[0]);
            prow[(rb + 1) * 80 + 16 + c] = f2bf(a1[1]);
            prow[(rb + 2) * 80 + 16 + c] = f2bf(a1[2]);
            prow[(rb + 3) * 80 + 16 + c] = f2bf(a1[3]);
            prow[(rb + 0) * 80 + 32 + c] = f2bf(a2[0]);
            prow[(rb + 1) * 80 + 32 + c] = f2bf(a2[1]);
            prow[(rb + 2) * 80 + 32 + c] = f2bf(a2[2]);
            prow[(rb + 3) * 80 + 32 + c] = f2bf(a2[3]);
            prow[(rb + 0) * 80 + 48 + c] = f2bf(a3[0]);
            prow[(rb + 1) * 80 + 48 + c] = f2bf(a3[1]);
            prow[(rb + 2) * 80 + 48 + c] = f2bf(a3[2]);
            prow[(rb + 3) * 80 + 48 + c] = f2bf(a3[3]);
        }

        {
            short8_t p0 = *(const short8_t*)&pf[wave][c][ 0 + g * 8];
            short8_t v00 = *(const short8_t*)&vf[cur][0][0][lane][0];
            short8_t v01 = *(const short8_t*)&vf[cur][0][1][lane][0];
            o0 = __builtin_amdgcn_mfma_f32_16x16x32_bf16(p0, v00, o0, 0, 0, 0);
            o1 = __builtin_amdgcn_mfma_f32_16x16x32_bf16(p0, v01, o1, 0, 0, 0);
            short8_t p1 = *(const short8_t*)&pf[wave][c][32 + g * 8];
            short8_t v10 = *(const short8_t*)&vf[cur][1][0][lane][0];
            short8_t v11 = *(const short8_t*)&vf[cur][1][1][lane][0];
            o0 = __builtin_amdgcn_mfma_f32_16x16x32_bf16(p1, v10, o0, 0, 0, 0);
            o1 = __builtin_amdgcn_mfma_f32_16x16x32_bf16(p1, v11, o1, 0, 0, 0);
        }

        __syncthreads();
        cur ^= 1;
    }

    int rec = ((s * NHH + head) * 64 + blockIdx.x) * NSPLIT + part;
    float* po = part_o + (size_t)rec * 2048;
    int qb = wave * 16 + g * 4;
    po[(qb + 0) * 32 + c] = o0[0];
    po[(qb + 1) * 32 + c] = o0[1];
    po[(qb + 2) * 32 + c] = o0[2];
    po[(qb + 3) * 32 + c] = o0[3];
    po[(qb + 0) * 32 + 16 + c] = o1[0];
    po[(qb + 1) * 32 + 16 + c] = o1[1];
    po[(qb + 2) * 32 + 16 + c] = o1[2];
    po[(qb + 3) * 32 + 16 + c] = o1[3];
    if (c == 0) {
        part_ml[rec * 128 + qb + 0] = mreg[0];
        part_ml[rec * 128 + qb + 1] = mreg[1];
        part_ml[rec * 128 + qb + 2] = mreg[2];
        part_ml[rec * 128 + qb + 3] = mreg[3];
        part_ml[rec * 128 + 64 + qb + 0] = lreg[0];
        part_ml[rec * 128 + 64 + qb + 1] = lreg[1];
        part_ml[rec * 128 + 64 + qb + 2] = lreg[2];
        part_ml[rec * 128 + 64 + qb + 3] = lreg[3];
    }
}

// ---------------- merge split-K partials ----------------
__global__ void k_attn_comb(const float* __restrict__ part_o, const float* __restrict__ part_ml,
                            float* __restrict__ attno,
                            const int* M0, const int* M1, const int* M2)
{
    int s = blockIdx.z, head = blockIdx.y;
    int Ms = getM(s, M0, M1, M2);
    int q0 = blockIdx.x * 64;
    if (q0 >= Ms) return;
    int tid = threadIdx.x;
    int qi = tid >> 2, sub = tid & 3;
    int nparts = (Ms + PLEN - 1) / PLEN;
    if (nparts > NSPLIT) nparts = NSPLIT;
    int recbase = ((s * NHH + head) * 64 + blockIdx.x) * NSPLIT;

    float m = -1e30f;
    for (int p = 0; p < nparts; ++p)
        m = fmaxf(m, part_ml[(recbase + p) * 128 + qi]);
    float L = 0.f;
    float4 A0 = {0,0,0,0}, A1 = {0,0,0,0};
    for (int p = 0; p < nparts; ++p) {
        float mp = part_ml[(recbase + p) * 128 + qi];
        float lp = part_ml[(recbase + p) * 128 + 64 + qi];
        float w = __expf(mp - m);
        L += lp * w;
        const float* po = part_o + (size_t)(recbase + p) * 2048;
        float4 a = *(const float4*)(po + qi * 32 + sub * 4);
        float4 b = *(const float4*)(po + qi * 32 + (sub + 4) * 4);
        A0.x += a.x * w; A0.y += a.y * w; A0.z += a.z * w; A0.w += a.w * w;
        A1.x += b.x * w; A1.y += b.y * w; A1.z += b.z * w; A1.w += b.w * w;
    }
    if (q0 + qi < Ms) {
        float inv = 1.0f / fmaxf(L, 1e-30f);
        size_t orow = ((size_t)s * MC + q0 + qi) * DD + head * DH;
        float4 r0 = make_float4(A0.x * inv, A0.y * inv, A0.z * inv, A0.w * inv);
        float4 r1 = make_float4(A1.x * inv, A1.y * inv, A1.z * inv, A1.w * inv);
        *(float4*)(attno + orow + sub * 4) = r0;
        *(float4*)(attno + orow + (sub + 4) * 4) = r1;
    }
}

// ---------------- fused LN1+FFN+LN2+yproj, 8 ROWS PER BLOCK ----------------
__global__ __launch_bounds__(256) void k_layer(const float* __restrict__ macro,
                                               const float* __restrict__ attno,
                                               const float* __restrict__ Wo, const float* __restrict__ bo,
                                               const float* __restrict__ ln1s, const float* __restrict__ ln1b,
                                               const float* __restrict__ W1, const float* __restrict__ b1,
                                               const float* __restrict__ W2, const float* __restrict__ b2,
                                               const float* __restrict__ ln2s, const float* __restrict__ ln2b,
                                               const float* __restrict__ Wf,
                                               float* __restrict__ y,
                                               const int* M0, const int* M1, const int* M2)
{
    int s = blockIdx.y;
    int Ms = getM(s, M0, M1, M2);
    int row0 = blockIdx.x * 8;
    if (row0 >= Ms) return;
    __shared__ __align__(16) float os8[8][DD];   // attno rows -> later x2 rows
    __shared__ __align__(16) float xr8[8][DD];   // x1 rows
    __shared__ __align__(16) float ts8[8][FFD];  // ffn hidden
    __shared__ float mv[8][2];
    int tid = threadIdx.x;  // 256
    int rr = tid >> 5, tt = tid & 31;   // (row, 32-lane slot) for stage/LN phases

    {
        int row = row0 + rr;
        float4 v = make_float4(0.f, 0.f, 0.f, 0.f);
        if (row < Ms) v = *(const float4*)(attno + ((size_t)s * MC + row) * DD + tt * 4);
        *(float4*)&os8[rr][tt * 4] = v;
    }
    __syncthreads();

    float acc[8];

    // ---- Wo proj + residual -> xr8 (pre-LN) ----
    if (tid < DD) {
        const float* w = Wo + ((size_t)s * DD + tid) * DD;
        float b = bo[s * DD + tid];
#pragma unroll
        for (int r = 0; r < 8; ++r) acc[r] = b;
        for (int k = 0; k < DD; k += 4) {
            float4 w4 = *(const float4*)(w + k);
#pragma unroll
            for (int r = 0; r < 8; ++r) {
                float4 m4 = *(const float4*)&os8[r][k];
                acc[r] += w4.x * m4.x + w4.y * m4.y + w4.z * m4.z + w4.w * m4.w;
            }
        }
#pragma unroll
        for (int r = 0; r < 8; ++r) {
            int row = row0 + r;
            float res = (row < Ms) ? macro[((size_t)s * MC + row) * DD + tid] : 0.f;
            xr8[r][tid] = acc[r] + res;
        }
    }
    __syncthreads();

    // ---- LN1 reduce (32 lanes per row) + apply ----
    {
        float4 v = *(const float4*)&xr8[rr][tt * 4];
        float su = v.x + v.y + v.z + v.w;
        float sq = v.x * v.x + v.y * v.y + v.z * v.z + v.w * v.w;
        for (int off = 16; off >= 1; off >>= 1) { su += __shfl_xor(su, off); sq += __shfl_xor(sq, off); }
        if (tt == 0) { mv[rr][0] = su; mv[rr][1] = sq; }
    }
    __syncthreads();
    {
        float mean = mv[rr][0] * (1.0f / DD);
        float var = fmaxf(mv[rr][1] * (1.0f / DD) - mean * mean, 0.0f);
        float rstd = rsqrtf(var + 1e-5f);
        float4 v = *(const float4*)&xr8[rr][tt * 4];
        float4 gs = *(const float4*)(ln1s + s * DD + tt * 4);
        float4 gb = *(const float4*)(ln1b + s * DD + tt * 4);
        float4 o;
        o.x = (v.x - mean) * rstd * gs.x + gb.x;
        o.y = (v.y - mean) * rstd * gs.y + gb.y;
        o.z = (v.z - mean) * rstd * gs.z + gb.z;
        o.w = (v.w - mean) * rstd * gs.w + gb.w;
        *(float4*)&xr8[rr][tt * 4] = o;
    }
    __syncthreads();

    // ---- FFN t1: ts8 = relu(xr8 @ W1.T + b1), all 256 threads ----
    {
        const float* w = W1 + ((size_t)s * FFD + tid) * DD;
        float b = b1[s * FFD + tid];
#pragma unroll
        for (int r = 0; r < 8; ++r) acc[r] = b;
        for (int k = 0; k < DD; k += 4) {
            float4 w4 = *(const float4*)(w + k);
#pragma unroll
            for (int r = 0; r < 8; ++r) {
                float4 m4 = *(const float4*)&xr8[r][k];
                acc[r] += w4.x * m4.x + w4.y * m4.y + w4.z * m4.z + w4.w * m4.w;
            }
        }
#pragma unroll
        for (int r = 0; r < 8; ++r) ts8[r][tid] = fmaxf(acc[r], 0.0f);
    }
    __syncthreads();

    // ---- FFN t2 + residual -> os8 (pre-LN) ----
    if (tid < DD) {
        const float* w = W2 + ((size_t)s * DD + tid) * FFD;
        float b = b2[s * DD + tid];
#pragma unroll
        for (int r = 0; r < 8; ++r) acc[r] = b;
        for (int k = 0; k < FFD; k += 4) {
            float4 w4 = *(const float4*)(w + k);
#pragma unroll
            for (int r = 0; r < 8; ++r) {
                float4 m4 = *(const float4*)&ts8[r][k];
                acc[r] += w4.x * m4.x + w4.y * m4.y + w4.z * m4.z + w4.w * m4.w;
            }
        }
#pragma unroll
        for (int r = 0; r < 8; ++r) os8[r][tid] = acc[r] + xr8[r][tid];
    }
    __syncthreads();

    // ---- LN2 reduce + apply -> os8 ----
    {
        float4 v = *(const float4*)&os8[rr][tt * 4];
        float su = v.x + v.y + v.z + v.w;
        float sq = v.x * v.x + v.y * v.y + v.z * v.z + v.w * v.w;
        for (int off = 16; off >= 1; off >>= 1) { su += __shfl_xor(su, off); sq += __shfl_xor(sq, off); }
        if (tt == 0) { mv[rr][0] = su; mv[rr][1] = sq; }
    }
    __syncthreads();
    {
        float mean = mv[rr][0] * (1.0f / DD);
        float var = fmaxf(mv[rr][1] * (1.0f / DD) - mean * mean, 0.0f);
        float rstd = rsqrtf(var + 1e-5f);
        float4 v = *(const float4*)&os8[rr][tt * 4];
        float4 gs = *(const float4*)(ln2s + s * DD + tt * 4);
        float4 gb = *(const float4*)(ln2b + s * DD + tt * 4);
        float4 o;
        o.x = (v.x - mean) * rstd * gs.x + gb.x;
        o.y = (v.y - mean) * rstd * gs.y + gb.y;
        o.z = (v.z - mean) * rstd * gs.z + gb.z;
        o.w = (v.w - mean) * rstd * gs.w + gb.w;
        *(float4*)&os8[rr][tt * 4] = o;
    }
    __syncthreads();

    // ---- yproj ----
    if (tid < DD) {
        const float* w = Wf + (size_t)tid * (4 * DD) + (s + 1) * DD;
#pragma unroll
        for (int r = 0; r < 8; ++r) acc[r] = 0.f;
        for (int k = 0; k < DD; k += 4) {
            float4 w4 = *(const float4*)(w + k);
#pragma unroll
            for (int r = 0; r < 8; ++r) {
                float4 m4 = *(const float4*)&os8[r][k];
                acc[r] += w4.x * m4.x + w4.y * m4.y + w4.z * m4.z + w4.w * m4.w;
            }
        }
#pragma unroll
        for (int r = 0; r < 8; ++r) {
            int row = row0 + r;
            if (row < Ms) y[((size_t)s * MC + row) * DD + tid] = acc[r];
        }
    }
}

// ---------------- yc[v] = y0[v] + y1[parent10[v]] + y2[parent21[parent10[v]]] + bf ----------------
// R18: RESTORED (R17's removal regressed k_final 110->177us: with full-line paired
// stores, the 3-gather epilogue is the limiter; yc cuts gathers 24->8 per lane-pair).
__global__ void k_ycomb(const float* __restrict__ y, const int* __restrict__ parent10,
                        const int* __restrict__ parent21, const float* __restrict__ bf,
                        float* __restrict__ yc, const int* __restrict__ M0)
{
    int idx = blockIdx.x * 256 + threadIdx.x;   // < MC*DD
    int v = idx >> 7, d = idx & 127;
    if (v >= *M0) return;
    int p1 = parent10[v];
    int p2 = parent21[p1];
    yc[idx] = y[(size_t)v * DD + d] + y[((size_t)MC + p1) * DD + d]
            + y[((size_t)2 * MC + p2) * DD + d] + bf[d];
}

// ---------------- out = h@B0 (bf16 MFMA) + yc[inv0] : 2 tasks/wave, PAIRED-nt stores ----------------
__global__ __launch_bounds__(256) void k_final(const float* __restrict__ h,
                                               const unsigned short* __restrict__ b0f,
                                               const float* __restrict__ yc,
                                               const int* __restrict__ inv0,
                                               float* __restrict__ out, int N)
{
    int tid = threadIdx.x;
    int wave = tid >> 6, lane = tid & 63;
    int c = lane & 15, g = lane >> 4;

    int ntasks = (N + 15) >> 4;
    int pair = blockIdx.x * 4 + wave;
    int taskA = pair * 2;
    if (taskA >= ntasks) return;
    int taskB = taskA + 1;

    int pA = taskA * 16 + c;
    int pB = taskB * 16 + c;
    bool okA = (pA < N);
    bool okB = (taskB < ntasks) && (pB < N);

    short8_t hA0 = {0,0,0,0,0,0,0,0}, hA1 = hA0, hA2 = hA0, hA3 = hA0;
    short8_t hB0 = hA0, hB1 = hA0, hB2 = hA0, hB3 = hA0;
    int iA = 0, iB = 0;
    if (okA) {
        const float* hr = h + (size_t)pA * DD + g * 8;
        hA0 = pack8(*(const float4*)(hr +  0), *(const float4*)(hr +  4));
        hA1 = pack8(*(const float4*)(hr + 32), *(const float4*)(hr + 36));
        hA2 = pack8(*(const float4*)(hr + 64), *(const float4*)(hr + 68));
        hA3 = pack8(*(const float4*)(hr + 96), *(const float4*)(hr + 100));
        iA = inv0[pA];
    }
    if (okB) {
        const float* hr = h + (size_t)pB * DD + g * 8;
        hB0 = pack8(*(const float4*)(hr +  0), *(const float4*)(hr +  4));
        hB1 = pack8(*(const float4*)(hr + 32), *(const float4*)(hr + 36));
        hB2 = pack8(*(const float4*)(hr + 64), *(const float4*)(hr + 68));
        hB3 = pack8(*(const float4*)(hr + 96), *(const float4*)(hr + 100));
        iB = inv0[pB];
    }
    const float* ycA = yc + (size_t)iA * DD;
    const float* ycB = yc + (size_t)iB * DD;

#pragma unroll
    for (int ntp = 0; ntp < 4; ++ntp) {
        int nt0 = ntp * 2, nt1 = ntp * 2 + 1;
        f32x4 aA0 = {0.f, 0.f, 0.f, 0.f}, aA1 = {0.f, 0.f, 0.f, 0.f};
        f32x4 aB0 = {0.f, 0.f, 0.f, 0.f}, aB1 = {0.f, 0.f, 0.f, 0.f};
        {
            short8_t w00 = *(const short8_t*)(b0f + (size_t)((nt0 * 4 + 0) * 64 + lane) * 8);
            aA0 = __builtin_amdgcn_mfma_f32_16x16x32_bf16(w00, hA0, aA0, 0, 0, 0);
            aB0 = __builtin_amdgcn_mfma_f32_16x16x32_bf16(w00, hB0, aB0, 0, 0, 0);
            short8_t w10 = *(const short8_t*)(b0f + (size_t)((nt1 * 4 + 0) * 64 + lane) * 8);
            aA1 = __builtin_amdgcn_mfma_f32_16x16x32_bf16(w10, hA0, aA1, 0, 0, 0);
            aB1 = __builtin_amdgcn_mfma_f32_16x16x32_bf16(w10, hB0, aB1, 0, 0, 0);
            short8_t w01 = *(const short8_t*)(b0f + (size_t)((nt0 * 4 + 1) * 64 + lane) * 8);
            aA0 = __builtin_amdgcn_mfma_f32_16x16x32_bf16(w01, hA1, aA0, 0, 0, 0);
            aB0 = __builtin_amdgcn_mfma_f32_16x16x32_bf16(w01, hB1, aB0, 0, 0, 0);
            short8_t w11 = *(const short8_t*)(b0f + (size_t)((nt1 * 4 + 1) * 64 + lane) * 8);
            aA1 = __builtin_amdgcn_mfma_f32_16x16x32_bf16(w11, hA1, aA1, 0, 0, 0);
            aB1 = __builtin_amdgcn_mfma_f32_16x16x32_bf16(w11, hB1, aB1, 0, 0, 0);
            short8_t w02 = *(const short8_t*)(b0f + (size_t)((nt0 * 4 + 2) * 64 + lane) * 8);
            aA0 = __builtin_amdgcn_mfma_f32_16x16x32_bf16(w02, hA2, aA0, 0, 0, 0);
            aB0 = __builtin_amdgcn_mfma_f32_16x16x32_bf16(w02, hB2, aB0, 0, 0, 0);
            short8_t w12 = *(const short8_t*)(b0f + (size_t)((nt1 * 4 + 2) * 64 + lane) * 8);
            aA1 = __builtin_amdgcn_mfma_f32_16x16x32_bf16(w12, hA2, aA1, 0, 0, 0);
            aB1 = __builtin_amdgcn_mfma_f32_16x16x32_bf16(w12, hB2, aB1, 0, 0, 0);
            short8_t w03 = *(const short8_t*)(b0f + (size_t)((nt0 * 4 + 3) * 64 + lane) * 8);
            aA0 = __builtin_amdgcn_mfma_f32_16x16x32_bf16(w03, hA3, aA0, 0, 0, 0);
            aB0 = __builtin_amdgcn_mfma_f32_16x16x32_bf16(w03, hB3, aB0, 0, 0, 0);
            short8_t w13 = *(const short8_t*)(b0f + (size_t)((nt1 * 4 + 3) * 64 + lane) * 8);
            aA1 = __builtin_amdgcn_mfma_f32_16x16x32_bf16(w13, hA3, aA1, 0, 0, 0);
            aB1 = __builtin_amdgcn_mfma_f32_16x16x32_bf16(w13, hB3, aB1, 0, 0, 0);
        }
        int d0 = nt0 * 16 + g * 4;
        int d1 = d0 + 16;
        if (okA) {
            float4 g0 = *(const float4*)(ycA + d0);
            float4 g1 = *(const float4*)(ycA + d1);
            float4 r0, r1;
            r0.x = aA0[0] + g0.x; r0.y = aA0[1] + g0.y; r0.z = aA0[2] + g0.z; r0.w = aA0[3] + g0.w;
            r1.x = aA1[0] + g1.x; r1.y = aA1[1] + g1.y; r1.z = aA1[2] + g1.z; r1.w = aA1[3] + g1.w;
            *(float4*)(out + (size_t)pA * DD + d0) = r0;
            *(float4*)(out + (size_t)pA * DD + d1) = r1;
        }
        if (okB) {
            float4 g0 = *(const float4*)(ycB + d0);
            float4 g1 = *(const float4*)(ycB + d1);
            float4 r0, r1;
            r0.x = aB0[0] + g0.x; r0.y = aB0[1] + g0.y; r0.z = aB0[2] + g0.z; r0.w = aB0[3] + g0.w;
            r1.x = aB1[0] + g1.x; r1.y = aB1[1] + g1.y; r1.z = aB1[2] + g1.z; r1.w = aB1[3] + g1.w;
            *(float4*)(out + (size_t)pB * DD + d0) = r0;
            *(float4*)(out + (size_t)pB * DD + d1) = r1;
        }
    }
}

extern "C" void kernel_launch(void* const* d_in, const int* in_sizes, int n_in,
                              void* d_out, int out_size, void* d_ws, size_t ws_size,
                              hipStream_t stream) {
    (void)n_in; (void)out_size; (void)ws_size;
    const float* h   = (const float*)d_in[0];
    const int* inv0  = (const int*)d_in[2];
    const int* inv1  = (const int*)d_in[3];
    const int* inv2  = (const int*)d_in[4];
    const int* M0    = (const int*)d_in[5];
    const int* M1    = (const int*)d_in[6];
    const int* M2    = (const int*)d_in[7];
    const float* Wqkv = (const float*)d_in[8];
    const float* bqkv = (const float*)d_in[9];
    const float* Wo   = (const float*)d_in[10];
    const float* bo   = (const float*)d_in[11];
    const float* ln1s = (const float*)d_in[12];
    const float* ln1b = (const float*)d_in[13];
    const float* W1   = (const float*)d_in[14];
    const float* b1   = (const float*)d_in[15];
    const float* W2   = (const float*)d_in[16];
    const float* b2   = (const float*)d_in[17];
    const float* ln2s = (const float*)d_in[18];
    const float* ln2b = (const float*)d_in[19];
    const float* Wf   = (const float*)d_in[20];
    const float* bf   = (const float*)d_in[21];
    int N = in_sizes[0] / DD;

    float* ws      = (float*)d_ws;
    float* macro   = ws;                                    // NS*MC*DD
    float* counts  = macro + (size_t)NS * MC * DD;          // NS*MC
    float* qkvb    = counts + (size_t)NS * MC;              // NS*MC*3*DD
    float* attno   = qkvb + (size_t)NS * MC * 3 * DD;       // NS*MC*DD
    float* yb      = attno + (size_t)NS * MC * DD;          // NS*MC*DD
    float* b0f_f   = yb + (size_t)NS * MC * DD;             // DD*DD floats of space (b0f uses half)
    unsigned short* b0f = (unsigned short*)b0f_f;
    float* part_o  = b0f_f + (size_t)DD * DD;               // NS*NHH*64*NSPLIT*2048
    float* part_ml = part_o + (size_t)NS * NHH * 64 * NSPLIT * 2048;  // NS*NHH*64*NSPLIT*128
    float* ycb     = part_ml + (size_t)NS * NHH * 64 * NSPLIT * 128;  // MC*DD
    int* ip        = (int*)(ycb + (size_t)MC * DD);
    int* parent10  = ip;                // MC
    int* parent21  = parent10 + MC;     // 512
    int* cnt_i     = parent21 + 512;    // MC
    int* fill      = cnt_i + MC;        // MC
    int* offs      = fill + MC;         // MC
    int* order     = offs + MC;         // N

    float* sum0 = macro;
    float* sum1 = macro + (size_t)1 * MC * DD;
    float* sum2 = macro + (size_t)2 * MC * DD;
    float* cnt0 = counts;
    float* cnt1 = counts + MC;
    float* cnt2 = counts + 2 * MC;

    hipMemsetAsync(macro, 0, ((size_t)NS * MC * DD + NS * MC) * sizeof(float), stream);
    hipMemsetAsync(cnt_i, 0, (size_t)2 * MC * sizeof(int), stream);

    int nb = (N + 255) / 256;
    k_parent<<<nb, 256, 0, stream>>>(inv0, inv1, inv2, parent10, parent21, cnt_i, N);
    k_scan<<<1, 1024, 0, stream>>>(cnt_i, offs);
    k_place<<<nb, 256, 0, stream>>>(inv0, offs, fill, order, N);
    k_pool<<<MC, 256, 0, stream>>>(h, order, offs, cnt_i, sum0, cnt0, M0);
    k_rollup_both<<<(MC * DD) / 256, 256, 0, stream>>>(sum0, cnt0, parent10, parent21,
                                                       sum1, cnt1, sum2, cnt2, M0);
    k_finalize<<<(NS * MC * DD + DD * DD) / 256, 256, 0, stream>>>(macro, counts, Wf, b0f, M0, M1, M2);
    k_qkv<<<dim3(MC / 8, NS), 256, 0, stream>>>(macro, Wqkv, bqkv, qkvb, M0, M1, M2);
    k_attn_part<<<dim3(MC / 64, NHH, NS * NSPLIT), 256, 0, stream>>>(qkvb, part_o, part_ml, M0, M1, M2);
    k_attn_comb<<<dim3(MC / 64, NHH, NS), 256, 0, stream>>>(part_o, part_ml, attno, M0, M1, M2);
    k_layer<<<dim3(MC / 8, NS), 256, 0, stream>>>(macro, attno, Wo, bo, ln1s, ln1b,
                                                  W1, b1, W2, b2, ln2s, ln2b, Wf, yb, M0, M1, M2);
    k_ycomb<<<(MC * DD) / 256, 256, 0, stream>>>(yb, parent10, parent21, bf, ycb, M0);
    int ntasks = (N + 15) >> 4;
    int npairs = (ntasks + 1) / 2;
    k_final<<<(npairs + 3) / 4, 256, 0, stream>>>(h, b0f, ycb, inv0, (float*)d_out, N);
}

// Round 20
// 460.434 us; speedup vs baseline: 1.1371x; 1.0393x over previous
//
#include <hip/hip_runtime.h>
#include <hip/hip_bf16.h>

#define MC 4096
#define DD 128
#define NHH 4
#define DH 32
#define FFD 256
#define NS 3
#define NSPLIT 4
#define PLEN 1024

typedef __attribute__((ext_vector_type(8))) short short8_t;
typedef __attribute__((ext_vector_type(4))) float f32x4;

__device__ __forceinline__ int getM(int s, const int* M0, const int* M1, const int* M2) {
    return (s == 0) ? *M0 : (s == 1) ? *M1 : *M2;
}

__device__ __forceinline__ unsigned short f2bf(float f) {
    unsigned int u = __float_as_uint(f);
    u += 0x7FFFu + ((u >> 16) & 1u);   // RNE
    return (unsigned short)(u >> 16);
}

__device__ __forceinline__ short8_t pack8(float4 a, float4 b) {
    short8_t r;
    r[0] = (short)f2bf(a.x); r[1] = (short)f2bf(a.y);
    r[2] = (short)f2bf(a.z); r[3] = (short)f2bf(a.w);
    r[4] = (short)f2bf(b.x); r[5] = (short)f2bf(b.y);
    r[6] = (short)f2bf(b.z); r[7] = (short)f2bf(b.w);
    return r;
}

__device__ __forceinline__ f32x4 max4(f32x4 a, f32x4 b) {
    f32x4 r;
    r[0] = fmaxf(a[0], b[0]); r[1] = fmaxf(a[1], b[1]);
    r[2] = fmaxf(a[2], b[2]); r[3] = fmaxf(a[3], b[3]);
    return r;
}
__device__ __forceinline__ f32x4 shflx4(f32x4 a, int m) {
    f32x4 r;
    r[0] = __shfl_xor(a[0], m); r[1] = __shfl_xor(a[1], m);
    r[2] = __shfl_xor(a[2], m); r[3] = __shfl_xor(a[3], m);
    return r;
}
__device__ __forceinline__ f32x4 exp4(f32x4 a) {
    f32x4 r;
    r[0] = __expf(a[0]); r[1] = __expf(a[1]);
    r[2] = __expf(a[2]); r[3] = __expf(a[3]);
    return r;
}

// ---------------- parent maps + scale-0 histogram in one pass ----------------
__global__ void k_parent(const int* __restrict__ inv0, const int* __restrict__ inv1,
                         const int* __restrict__ inv2,
                         int* __restrict__ parent10, int* __restrict__ parent21,
                         int* __restrict__ cnt, int N)
{
    int n = blockIdx.x * blockDim.x + threadIdx.x;
    if (n >= N) return;
    int i0 = inv0[n];
    parent10[i0] = inv1[n];   // duplicate writes all agree (grids nest)
    parent21[inv1[n]] = inv2[n];
    atomicAdd(&cnt[i0], 1);
}

// ---------------- exclusive scan over MC=4096 bins, single block 1024 thr ----------------
__global__ void k_scan(const int* __restrict__ cnt, int* __restrict__ offs)
{
    __shared__ int arr[1024];
    int tid = threadIdx.x;
    int base = tid * 4;
    int c0 = cnt[base], c1 = cnt[base + 1], c2 = cnt[base + 2], c3 = cnt[base + 3];
    int tot = c0 + c1 + c2 + c3;
    arr[tid] = tot;
    __syncthreads();
    for (int off = 1; off < 1024; off <<= 1) {
        int v = (tid >= off) ? arr[tid - off] : 0;
        __syncthreads();
        arr[tid] += v;
        __syncthreads();
    }
    int excl = arr[tid] - tot;
    offs[base] = excl;
    offs[base + 1] = excl + c0;
    offs[base + 2] = excl + c0 + c1;
    offs[base + 3] = excl + c0 + c1 + c2;
}

// ---------------- placement: order[] groups particles by voxel ----------------
__global__ void k_place(const int* __restrict__ inv0, const int* __restrict__ offs,
                        int* __restrict__ fill, int* __restrict__ order, int N)
{
    int n = blockIdx.x * blockDim.x + threadIdx.x;
    if (n >= N) return;
    int i0 = inv0[n];
    int pos = offs[i0] + atomicAdd(&fill[i0], 1);
    order[pos] = n;
}

// ---------------- pooled sums: float4/thread, 8 row-slots, 2x unrolled ----------------
__global__ __launch_bounds__(256) void k_pool(const float* __restrict__ h,
                                              const int* __restrict__ order,
                                              const int* __restrict__ offs,
                                              const int* __restrict__ cnt,
                                              float* __restrict__ sum0, float* __restrict__ cnt0,
                                              const int* __restrict__ M0)
{
    int v = blockIdx.x;
    if (v >= *M0) return;
    int beg = offs[v], len = cnt[v];
    int tid = threadIdx.x;
    int dg = tid & 31;          // dim group: dims dg*4 .. dg*4+3
    int rs = tid >> 5;          // row slot 0..7
    const int* op = order + beg;

    float ax = 0.f, ay = 0.f, az = 0.f, aw = 0.f;
    int j = rs;
    for (; j + 8 < len; j += 16) {
        int r0 = op[j];
        int r1 = op[j + 8];
        float4 a = *(const float4*)(h + (size_t)r0 * DD + dg * 4);
        float4 b = *(const float4*)(h + (size_t)r1 * DD + dg * 4);
        ax += a.x + b.x; ay += a.y + b.y; az += a.z + b.z; aw += a.w + b.w;
    }
    if (j < len) {
        int r0 = op[j];
        float4 a = *(const float4*)(h + (size_t)r0 * DD + dg * 4);
        ax += a.x; ay += a.y; az += a.z; aw += a.w;
    }

    __shared__ __align__(16) float red[8][DD];
    *(float4*)&red[rs][dg * 4] = make_float4(ax, ay, az, aw);
    __syncthreads();
    if (tid < 32) {
        float4 t0 = *(const float4*)&red[0][tid * 4];
        float4 t1 = *(const float4*)&red[1][tid * 4];
        float4 t2 = *(const float4*)&red[2][tid * 4];
        float4 t3 = *(const float4*)&red[3][tid * 4];
        float4 t4 = *(const float4*)&red[4][tid * 4];
        float4 t5 = *(const float4*)&red[5][tid * 4];
        float4 t6 = *(const float4*)&red[6][tid * 4];
        float4 t7 = *(const float4*)&red[7][tid * 4];
        float4 r;
        r.x = ((t0.x + t1.x) + (t2.x + t3.x)) + ((t4.x + t5.x) + (t6.x + t7.x));
        r.y = ((t0.y + t1.y) + (t2.y + t3.y)) + ((t4.y + t5.y) + (t6.y + t7.y));
        r.z = ((t0.z + t1.z) + (t2.z + t3.z)) + ((t4.z + t5.z) + (t6.z + t7.z));
        r.w = ((t0.w + t1.w) + (t2.w + t3.w)) + ((t4.w + t5.w) + (t6.w + t7.w));
        *(float4*)(sum0 + (size_t)v * DD + tid * 4) = r;
        if (tid == 0) cnt0[v] = (float)len;
    }
}

// ---------------- roll coarse sums up the hierarchy (two-stage: low contention) ----------------
__global__ void k_rollup(const float* __restrict__ sumSrc, const float* __restrict__ cntSrc,
                         const int* __restrict__ parent,
                         float* __restrict__ sumDst, float* __restrict__ cntDst,
                         const int* __restrict__ Msrc, int cap)
{
    int idx = blockIdx.x * blockDim.x + threadIdx.x;   // < cap*DD
    int v = idx >> 7, d = idx & 127;
    int Ms = *Msrc;
    if (Ms > cap) Ms = cap;
    if (v >= Ms) return;
    int p = parent[v];
    atomicAdd(&sumDst[(size_t)p * DD + d], sumSrc[idx]);
    if (d == 0) atomicAdd(&cntDst[p], cntSrc[v]);
}

// ---------------- divide by clamped counts ----------------
__global__ void k_finalize(float* __restrict__ macro, const float* __restrict__ counts,
                           const int* M0, const int* M1, const int* M2)
{
    int idx = blockIdx.x * blockDim.x + threadIdx.x;  // < NS*MC*DD
    int s = idx / (MC * DD);
    int r = (idx >> 7) & (MC - 1);
    if (r >= getM(s, M0, M1, M2)) return;
    float c = counts[s * MC + r];
    macro[idx] /= fmaxf(c, 1.0f);
}

// ---------------- b0frag: MFMA fragments of Wf[:, :128] in bf16 ----------------
__global__ void k_b0frag(const float* __restrict__ Wf, unsigned short* __restrict__ b0f)
{
    int idx = blockIdx.x * 256 + threadIdx.x;  // 16384
    int j = idx & 7, l = (idx >> 3) & 63, kt = (idx >> 9) & 3, nt = idx >> 11;
    int d = nt * 16 + (l & 15);
    int k = kt * 32 + (l >> 4) * 8 + j;
    b0f[idx] = f2bf(Wf[(size_t)d * (4 * DD) + k]);
}

// ---------------- qkv = macro @ Wqkv[s].T + bqkv[s], 8 rows/block ----------------
__global__ void k_qkv(const float* __restrict__ macro, const float* __restrict__ Wqkv,
                      const float* __restrict__ bqkv, float* __restrict__ qkv,
                      const int* M0, const int* M1, const int* M2)
{
    int s = blockIdx.y;
    int Ms = getM(s, M0, M1, M2);
    int row0 = blockIdx.x * 8;
    if (row0 >= Ms) return;
    __shared__ __align__(16) float mac[8][DD];
    int tid = threadIdx.x;
    for (int e = tid; e < 8 * DD; e += 256) {
        int r = e >> 7, d = e & 127;
        int row = row0 + r;
        mac[r][d] = (row < Ms) ? macro[(size_t)s * MC * DD + (size_t)row * DD + d] : 0.0f;
    }
    __syncthreads();
    for (int j = tid; j < 3 * DD; j += 256) {
        const float* w = Wqkv + ((size_t)s * 3 * DD + j) * DD;
        float b = bqkv[s * 3 * DD + j];
        float acc[8];
#pragma unroll
        for (int r = 0; r < 8; ++r) acc[r] = b;
        for (int k = 0; k < DD; k += 4) {
            float4 w4 = *(const float4*)(w + k);
#pragma unroll
            for (int r = 0; r < 8; ++r) {
                float4 m4 = *(const float4*)&mac[r][k];
                acc[r] += w4.x * m4.x + w4.y * m4.y + w4.z * m4.z + w4.w * m4.w;
            }
        }
        for (int r = 0; r < 8; ++r) {
            int row = row0 + r;
            if (row < Ms) qkv[((size_t)s * MC + row) * (3 * DD) + j] = acc[r];
        }
    }
}

// ---------------- MFMA flash attention partials, DOUBLE-BUFFERED staging ----------------
__global__ __launch_bounds__(256) void k_attn_part(const float* __restrict__ qkv,
                                                   float* __restrict__ part_o,
                                                   float* __restrict__ part_ml,
                                                   const int* M0, const int* M1, const int* M2)
{
    int z = blockIdx.z;
    int s = z / NSPLIT, part = z % NSPLIT;
    int head = blockIdx.y;
    int Ms = getM(s, M0, M1, M2);
    int q0 = blockIdx.x * 64;
    if (q0 >= Ms) return;
    int kstart = part * PLEN;
    if (kstart >= Ms) return;
    int kend = kstart + PLEN; if (kend > Ms) kend = Ms;

    __shared__ __align__(16) unsigned short kf[2][4][64][8];
    __shared__ __align__(16) unsigned short vf[2][2][2][64][8];
    __shared__ __align__(16) unsigned short pf[4][16][80];

    int tid = threadIdx.x;
    int wave = tid >> 6, lane = tid & 63;
    int c = lane & 15, g = lane >> 4;

    const float* base = qkv + (size_t)s * MC * 3 * DD;
    const float* Qb = base + head * DH;
    const float* Kb = base + DD + head * DH;
    const float* Vb = base + 2 * DD + head * DH;

    short8_t qfrag = {0,0,0,0,0,0,0,0};
    {
        int qr = q0 + wave * 16 + c;
        if (qr < Ms) {
            const float* qp = Qb + (size_t)qr * 3 * DD + g * 8;
            qfrag = pack8(*(const float4*)qp, *(const float4*)(qp + 4));
        }
    }

    f32x4 o0 = {0.f, 0.f, 0.f, 0.f}, o1 = {0.f, 0.f, 0.f, 0.f};
    f32x4 mreg = {-1e30f, -1e30f, -1e30f, -1e30f};
    f32x4 lreg = {0.f, 0.f, 0.f, 0.f};
    const float scale = 0.1767766952966369f;  // 1/sqrt(32)

    int sko = tid >> 2, sg = tid & 3;
    int s_nt = sko >> 4;
    int s_l  = (sko & 15) | (sg << 4);
    int s_ks = sko >> 5, s_kk = sko & 31;
    int s_j  = s_kk & 7, s_hi = (s_kk >> 3) & 3;
    int s_vnt = sg >> 1, s_db = (sg & 1) * 8;

    auto STAGE = [&](int buf, int kb) {
        {
            int key = kb + sko;
            short8_t kv = {0,0,0,0,0,0,0,0};
            if (key < kend) {
                const float* kr = Kb + (size_t)key * 3 * DD + sg * 8;
                kv = pack8(*(const float4*)kr, *(const float4*)(kr + 4));
            }
            *(short8_t*)&kf[buf][s_nt][s_l][0] = kv;
        }
        {
            int key = kb + sko;
            float4 a = make_float4(0.f, 0.f, 0.f, 0.f);
            float4 b = make_float4(0.f, 0.f, 0.f, 0.f);
            if (key < kend) {
                const float* vr = Vb + (size_t)key * 3 * DD + sg * 8;
                a = *(const float4*)vr;
                b = *(const float4*)(vr + 4);
            }
            unsigned short* vslot = &vf[buf][s_ks][s_vnt][0][0];
            vslot[((s_db + 0) | (s_hi << 4)) * 8 + s_j] = f2bf(a.x);
            vslot[((s_db + 1) | (s_hi << 4)) * 8 + s_j] = f2bf(a.y);
            vslot[((s_db + 2) | (s_hi << 4)) * 8 + s_j] = f2bf(a.z);
            vslot[((s_db + 3) | (s_hi << 4)) * 8 + s_j] = f2bf(a.w);
            vslot[((s_db + 4) | (s_hi << 4)) * 8 + s_j] = f2bf(b.x);
            vslot[((s_db + 5) | (s_hi << 4)) * 8 + s_j] = f2bf(b.y);
            vslot[((s_db + 6) | (s_hi << 4)) * 8 + s_j] = f2bf(b.z);
            vslot[((s_db + 7) | (s_hi << 4)) * 8 + s_j] = f2bf(b.w);
        }
    };

    STAGE(0, kstart);
    __syncthreads();
    int cur = 0;

    for (int kb = kstart; kb < kend; kb += 64) {
        if (kb + 64 < kend) STAGE(cur ^ 1, kb + 64);

        f32x4 zero = {0.f, 0.f, 0.f, 0.f};
        short8_t kf0 = *(const short8_t*)&kf[cur][0][lane][0];
        short8_t kf1 = *(const short8_t*)&kf[cur][1][lane][0];
        short8_t kf2 = *(const short8_t*)&kf[cur][2][lane][0];
        short8_t kf3 = *(const short8_t*)&kf[cur][3][lane][0];
        f32x4 a0 = __builtin_amdgcn_mfma_f32_16x16x32_bf16(qfrag, kf0, zero, 0, 0, 0);
        f32x4 a1 = __builtin_amdgcn_mfma_f32_16x16x32_bf16(qfrag, kf1, zero, 0, 0, 0);
        f32x4 a2 = __builtin_amdgcn_mfma_f32_16x16x32_bf16(qfrag, kf2, zero, 0, 0, 0);
        f32x4 a3 = __builtin_amdgcn_mfma_f32_16x16x32_bf16(qfrag, kf3, zero, 0, 0, 0);

        f32x4 neg = {-1e30f, -1e30f, -1e30f, -1e30f};
        a0 = (kb +  0 + c < kend) ? a0 * scale : neg;
        a1 = (kb + 16 + c < kend) ? a1 * scale : neg;
        a2 = (kb + 32 + c < kend) ? a2 * scale : neg;
        a3 = (kb + 48 + c < kend) ? a3 * scale : neg;

        f32x4 rmax = max4(max4(a0, a1), max4(a2, a3));
        rmax = max4(rmax, shflx4(rmax, 1));
        rmax = max4(rmax, shflx4(rmax, 2));
        rmax = max4(rmax, shflx4(rmax, 4));
        rmax = max4(rmax, shflx4(rmax, 8));
        f32x4 mnew = max4(mreg, rmax);
        f32x4 alpha = exp4(mreg - mnew);
        mreg = mnew;
        lreg = lreg * alpha;
        o0 = o0 * alpha;
        o1 = o1 * alpha;

        a0 = exp4(a0 - mnew);
        a1 = exp4(a1 - mnew);
        a2 = exp4(a2 - mnew);
        a3 = exp4(a3 - mnew);
        f32x4 rsum = (a0 + a1) + (a2 + a3);
        rsum = rsum + shflx4(rsum, 1);
        rsum = rsum + shflx4(rsum, 2);
        rsum = rsum + shflx4(rsum, 4);
        rsum = rsum + shflx4(rsum, 8);
        lreg = lreg + rsum;

        {
            unsigned short* prow = &pf[wave][0][0];
            int rb = g * 4;
            prow[(rb + 0) * 80 +  0 + c] = f2bf(a0[0]);
            prow[(rb + 1) * 80 +  0 + c] = f2bf(a0[1]);
            prow[(rb + 2) * 80 +  0 + c] = f2bf(a0[2]);
            prow[(rb + 3) * 80 +  0 + c] = f2bf(a0[3]);
            prow[(rb + 0) * 80 + 16 + c] = f2bf(a1[0]);
            prow[(rb + 1) * 80 + 16 + c] = f2bf(a1[1]);
            prow[(rb + 2) * 80 + 16 + c] = f2bf(a1[2]);
            prow[(rb + 3) * 80 + 16 + c] = f2bf(a1[3]);
            prow[(rb + 0) * 80 + 32 + c] = f2bf(a2[0]);
            prow[(rb + 1) * 80 + 32 + c] = f2bf(a2[1]);
            prow[(rb + 2) * 80 + 32 + c] = f2bf(a2[2]);
            prow[(rb + 3) * 80 + 32 + c] = f2bf(a2[3]);
            prow[(rb + 0) * 80 + 48 + c] = f2bf(a3[0]);
            prow[(rb + 1) * 80 + 48 + c] = f2bf(a3[1]);
            prow[(rb + 2) * 80 + 48 + c] = f2bf(a3[2]);
            prow[(rb + 3) * 80 + 48 + c] = f2bf(a3[3]);
        }

        {
            short8_t p0 = *(const short8_t*)&pf[wave][c][ 0 + g * 8];
            short8_t v00 = *(const short8_t*)&vf[cur][0][0][lane][0];
            short8_t v01 = *(const short8_t*)&vf[cur][0][1][lane][0];
            o0 = __builtin_amdgcn_mfma_f32_16x16x32_bf16(p0, v00, o0, 0, 0, 0);
            o1 = __builtin_amdgcn_mfma_f32_16x16x32_bf16(p0, v01, o1, 0, 0, 0);
            short8_t p1 = *(const short8_t*)&pf[wave][c][32 + g * 8];
            short8_t v10 = *(const short8_t*)&vf[cur][1][0][lane][0];
            short8_t v11 = *(const short8_t*)&vf[cur][1][1][lane][0];
            o0 = __builtin_amdgcn_mfma_f32_16x16x32_bf16(p1, v10, o0, 0, 0, 0);
            o1 = __builtin_amdgcn_mfma_f32_16x16x32_bf16(p1, v11, o1, 0, 0, 0);
        }

        __syncthreads();
        cur ^= 1;
    }

    int rec = ((s * NHH + head) * 64 + blockIdx.x) * NSPLIT + part;
    float* po = part_o + (size_t)rec * 2048;
    int qb = wave * 16 + g * 4;
    po[(qb + 0) * 32 + c] = o0[0];
    po[(qb + 1) * 32 + c] = o0[1];
    po[(qb + 2) * 32 + c] = o0[2];
    po[(qb + 3) * 32 + c] = o0[3];
    po[(qb + 0) * 32 + 16 + c] = o1[0];
    po[(qb + 1) * 32 + 16 + c] = o1[1];
    po[(qb + 2) * 32 + 16 + c] = o1[2];
    po[(qb + 3) * 32 + 16 + c] = o1[3];
    if (c == 0) {
        part_ml[rec * 128 + qb + 0] = mreg[0];
        part_ml[rec * 128 + qb + 1] = mreg[1];
        part_ml[rec * 128 + qb + 2] = mreg[2];
        part_ml[rec * 128 + qb + 3] = mreg[3];
        part_ml[rec * 128 + 64 + qb + 0] = lreg[0];
        part_ml[rec * 128 + 64 + qb + 1] = lreg[1];
        part_ml[rec * 128 + 64 + qb + 2] = lreg[2];
        part_ml[rec * 128 + 64 + qb + 3] = lreg[3];
    }
}

// ---------------- merge split-K partials ----------------
__global__ void k_attn_comb(const float* __restrict__ part_o, const float* __restrict__ part_ml,
                            float* __restrict__ attno,
                            const int* M0, const int* M1, const int* M2)
{
    int s = blockIdx.z, head = blockIdx.y;
    int Ms = getM(s, M0, M1, M2);
    int q0 = blockIdx.x * 64;
    if (q0 >= Ms) return;
    int tid = threadIdx.x;
    int qi = tid >> 2, sub = tid & 3;
    int nparts = (Ms + PLEN - 1) / PLEN;
    if (nparts > NSPLIT) nparts = NSPLIT;
    int recbase = ((s * NHH + head) * 64 + blockIdx.x) * NSPLIT;

    float m = -1e30f;
    for (int p = 0; p < nparts; ++p)
        m = fmaxf(m, part_ml[(recbase + p) * 128 + qi]);
    float L = 0.f;
    float4 A0 = {0,0,0,0}, A1 = {0,0,0,0};
    for (int p = 0; p < nparts; ++p) {
        float mp = part_ml[(recbase + p) * 128 + qi];
        float lp = part_ml[(recbase + p) * 128 + 64 + qi];
        float w = __expf(mp - m);
        L += lp * w;
        const float* po = part_o + (size_t)(recbase + p) * 2048;
        float4 a = *(const float4*)(po + qi * 32 + sub * 4);
        float4 b = *(const float4*)(po + qi * 32 + (sub + 4) * 4);
        A0.x += a.x * w; A0.y += a.y * w; A0.z += a.z * w; A0.w += a.w * w;
        A1.x += b.x * w; A1.y += b.y * w; A1.z += b.z * w; A1.w += b.w * w;
    }
    if (q0 + qi < Ms) {
        float inv = 1.0f / fmaxf(L, 1e-30f);
        size_t orow = ((size_t)s * MC + q0 + qi) * DD + head * DH;
        float4 r0 = make_float4(A0.x * inv, A0.y * inv, A0.z * inv, A0.w * inv);
        float4 r1 = make_float4(A1.x * inv, A1.y * inv, A1.z * inv, A1.w * inv);
        *(float4*)(attno + orow + sub * 4) = r0;
        *(float4*)(attno + orow + (sub + 4) * 4) = r1;
    }
}

// ---------------- fused LN1+FFN+LN2+yproj, 8 ROWS PER BLOCK ----------------
__global__ __launch_bounds__(256) void k_layer(const float* __restrict__ macro,
                                               const float* __restrict__ attno,
                                               const float* __restrict__ Wo, const float* __restrict__ bo,
                                               const float* __restrict__ ln1s, const float* __restrict__ ln1b,
                                               const float* __restrict__ W1, const float* __restrict__ b1,
                                               const float* __restrict__ W2, const float* __restrict__ b2,
                                               const float* __restrict__ ln2s, const float* __restrict__ ln2b,
                                               const float* __restrict__ Wf,
                                               float* __restrict__ y,
                                               const int* M0, const int* M1, const int* M2)
{
    int s = blockIdx.y;
    int Ms = getM(s, M0, M1, M2);
    int row0 = blockIdx.x * 8;
    if (row0 >= Ms) return;
    __shared__ __align__(16) float os8[8][DD];   // attno rows -> later x2 rows
    __shared__ __align__(16) float xr8[8][DD];   // x1 rows
    __shared__ __align__(16) float ts8[8][FFD];  // ffn hidden
    __shared__ float mv[8][2];
    int tid = threadIdx.x;  // 256
    int rr = tid >> 5, tt = tid & 31;   // (row, 32-lane slot) for stage/LN phases

    {
        int row = row0 + rr;
        float4 v = make_float4(0.f, 0.f, 0.f, 0.f);
        if (row < Ms) v = *(const float4*)(attno + ((size_t)s * MC + row) * DD + tt * 4);
        *(float4*)&os8[rr][tt * 4] = v;
    }
    __syncthreads();

    float acc[8];

    // ---- Wo proj + residual -> xr8 (pre-LN) ----
    if (tid < DD) {
        const float* w = Wo + ((size_t)s * DD + tid) * DD;
        float b = bo[s * DD + tid];
#pragma unroll
        for (int r = 0; r < 8; ++r) acc[r] = b;
        for (int k = 0; k < DD; k += 4) {
            float4 w4 = *(const float4*)(w + k);
#pragma unroll
            for (int r = 0; r < 8; ++r) {
                float4 m4 = *(const float4*)&os8[r][k];
                acc[r] += w4.x * m4.x + w4.y * m4.y + w4.z * m4.z + w4.w * m4.w;
            }
        }
#pragma unroll
        for (int r = 0; r < 8; ++r) {
            int row = row0 + r;
            float res = (row < Ms) ? macro[((size_t)s * MC + row) * DD + tid] : 0.f;
            xr8[r][tid] = acc[r] + res;
        }
    }
    __syncthreads();

    // ---- LN1 reduce (32 lanes per row) + apply ----
    {
        float4 v = *(const float4*)&xr8[rr][tt * 4];
        float su = v.x + v.y + v.z + v.w;
        float sq = v.x * v.x + v.y * v.y + v.z * v.z + v.w * v.w;
        for (int off = 16; off >= 1; off >>= 1) { su += __shfl_xor(su, off); sq += __shfl_xor(sq, off); }
        if (tt == 0) { mv[rr][0] = su; mv[rr][1] = sq; }
    }
    __syncthreads();
    {
        float mean = mv[rr][0] * (1.0f / DD);
        float var = fmaxf(mv[rr][1] * (1.0f / DD) - mean * mean, 0.0f);
        float rstd = rsqrtf(var + 1e-5f);
        float4 v = *(const float4*)&xr8[rr][tt * 4];
        float4 gs = *(const float4*)(ln1s + s * DD + tt * 4);
        float4 gb = *(const float4*)(ln1b + s * DD + tt * 4);
        float4 o;
        o.x = (v.x - mean) * rstd * gs.x + gb.x;
        o.y = (v.y - mean) * rstd * gs.y + gb.y;
        o.z = (v.z - mean) * rstd * gs.z + gb.z;
        o.w = (v.w - mean) * rstd * gs.w + gb.w;
        *(float4*)&xr8[rr][tt * 4] = o;
    }
    __syncthreads();

    // ---- FFN t1: ts8 = relu(xr8 @ W1.T + b1), all 256 threads ----
    {
        const float* w = W1 + ((size_t)s * FFD + tid) * DD;
        float b = b1[s * FFD + tid];
#pragma unroll
        for (int r = 0; r < 8; ++r) acc[r] = b;
        for (int k = 0; k < DD; k += 4) {
            float4 w4 = *(const float4*)(w + k);
#pragma unroll
            for (int r = 0; r < 8; ++r) {
                float4 m4 = *(const float4*)&xr8[r][k];
                acc[r] += w4.x * m4.x + w4.y * m4.y + w4.z * m4.z + w4.w * m4.w;
            }
        }
#pragma unroll
        for (int r = 0; r < 8; ++r) ts8[r][tid] = fmaxf(acc[r], 0.0f);
    }
    __syncthreads();

    // ---- FFN t2 + residual -> os8 (pre-LN) ----
    if (tid < DD) {
        const float* w = W2 + ((size_t)s * DD + tid) * FFD;
        float b = b2[s * DD + tid];
#pragma unroll
        for (int r = 0; r < 8; ++r) acc[r] = b;
        for (int k = 0; k < FFD; k += 4) {
            float4 w4 = *(const float4*)(w + k);
#pragma unroll
            for (int r = 0; r < 8; ++r) {
                float4 m4 = *(const float4*)&ts8[r][k];
                acc[r] += w4.x * m4.x + w4.y * m4.y + w4.z * m4.z + w4.w * m4.w;
            }
        }
#pragma unroll
        for (int r = 0; r < 8; ++r) os8[r][tid] = acc[r] + xr8[r][tid];
    }
    __syncthreads();

    // ---- LN2 reduce + apply -> os8 ----
    {
        float4 v = *(const float4*)&os8[rr][tt * 4];
        float su = v.x + v.y + v.z + v.w;
        float sq = v.x * v.x + v.y * v.y + v.z * v.z + v.w * v.w;
        for (int off = 16; off >= 1; off >>= 1) { su += __shfl_xor(su, off); sq += __shfl_xor(sq, off); }
        if (tt == 0) { mv[rr][0] = su; mv[rr][1] = sq; }
    }
    __syncthreads();
    {
        float mean = mv[rr][0] * (1.0f / DD);
        float var = fmaxf(mv[rr][1] * (1.0f / DD) - mean * mean, 0.0f);
        float rstd = rsqrtf(var + 1e-5f);
        float4 v = *(const float4*)&os8[rr][tt * 4];
        float4 gs = *(const float4*)(ln2s + s * DD + tt * 4);
        float4 gb = *(const float4*)(ln2b + s * DD + tt * 4);
        float4 o;
        o.x = (v.x - mean) * rstd * gs.x + gb.x;
        o.y = (v.y - mean) * rstd * gs.y + gb.y;
        o.z = (v.z - mean) * rstd * gs.z + gb.z;
        o.w = (v.w - mean) * rstd * gs.w + gb.w;
        *(float4*)&os8[rr][tt * 4] = o;
    }
    __syncthreads();

    // ---- yproj ----
    if (tid < DD) {
        const float* w = Wf + (size_t)tid * (4 * DD) + (s + 1) * DD;
#pragma unroll
        for (int r = 0; r < 8; ++r) acc[r] = 0.f;
        for (int k = 0; k < DD; k += 4) {
            float4 w4 = *(const float4*)(w + k);
#pragma unroll
            for (int r = 0; r < 8; ++r) {
                float4 m4 = *(const float4*)&os8[r][k];
                acc[r] += w4.x * m4.x + w4.y * m4.y + w4.z * m4.z + w4.w * m4.w;
            }
        }
#pragma unroll
        for (int r = 0; r < 8; ++r) {
            int row = row0 + r;
            if (row < Ms) y[((size_t)s * MC + row) * DD + tid] = acc[r];
        }
    }
}

// ---------------- yc[v] = y0[v] + y1[parent10[v]] + y2[parent21[parent10[v]]] + bf ----------------
__global__ void k_ycomb(const float* __restrict__ y, const int* __restrict__ parent10,
                        const int* __restrict__ parent21, const float* __restrict__ bf,
                        float* __restrict__ yc, const int* __restrict__ M0)
{
    int idx = blockIdx.x * 256 + threadIdx.x;   // < MC*DD
    int v = idx >> 7, d = idx & 127;
    if (v >= *M0) return;
    int p1 = parent10[v];
    int p2 = parent21[p1];
    yc[idx] = y[(size_t)v * DD + d] + y[((size_t)MC + p1) * DD + d]
            + y[((size_t)2 * MC + p2) * DD + d] + bf[d];
}

// ---------------- out = h@B0 (bf16 MFMA) + yc[inv0] : 2 tasks/wave, PAIRED-nt stores ----------------
__global__ __launch_bounds__(256) void k_final(const float* __restrict__ h,
                                               const unsigned short* __restrict__ b0f,
                                               const float* __restrict__ yc,
                                               const int* __restrict__ inv0,
                                               float* __restrict__ out, int N)
{
    int tid = threadIdx.x;
    int wave = tid >> 6, lane = tid & 63;
    int c = lane & 15, g = lane >> 4;

    int ntasks = (N + 15) >> 4;
    int pair = blockIdx.x * 4 + wave;
    int taskA = pair * 2;
    if (taskA >= ntasks) return;
    int taskB = taskA + 1;

    int pA = taskA * 16 + c;
    int pB = taskB * 16 + c;
    bool okA = (pA < N);
    bool okB = (taskB < ntasks) && (pB < N);

    short8_t hA0 = {0,0,0,0,0,0,0,0}, hA1 = hA0, hA2 = hA0, hA3 = hA0;
    short8_t hB0 = hA0, hB1 = hA0, hB2 = hA0, hB3 = hA0;
    int iA = 0, iB = 0;
    if (okA) {
        const float* hr = h + (size_t)pA * DD + g * 8;
        hA0 = pack8(*(const float4*)(hr +  0), *(const float4*)(hr +  4));
        hA1 = pack8(*(const float4*)(hr + 32), *(const float4*)(hr + 36));
        hA2 = pack8(*(const float4*)(hr + 64), *(const float4*)(hr + 68));
        hA3 = pack8(*(const float4*)(hr + 96), *(const float4*)(hr + 100));
        iA = inv0[pA];
    }
    if (okB) {
        const float* hr = h + (size_t)pB * DD + g * 8;
        hB0 = pack8(*(const float4*)(hr +  0), *(const float4*)(hr +  4));
        hB1 = pack8(*(const float4*)(hr + 32), *(const float4*)(hr + 36));
        hB2 = pack8(*(const float4*)(hr + 64), *(const float4*)(hr + 68));
        hB3 = pack8(*(const float4*)(hr + 96), *(const float4*)(hr + 100));
        iB = inv0[pB];
    }
    const float* ycA = yc + (size_t)iA * DD;
    const float* ycB = yc + (size_t)iB * DD;

#pragma unroll
    for (int ntp = 0; ntp < 4; ++ntp) {
        int nt0 = ntp * 2, nt1 = ntp * 2 + 1;
        f32x4 aA0 = {0.f, 0.f, 0.f, 0.f}, aA1 = {0.f, 0.f, 0.f, 0.f};
        f32x4 aB0 = {0.f, 0.f, 0.f, 0.f}, aB1 = {0.f, 0.f, 0.f, 0.f};
        {
            short8_t w00 = *(const short8_t*)(b0f + (size_t)((nt0 * 4 + 0) * 64 + lane) * 8);
            aA0 = __builtin_amdgcn_mfma_f32_16x16x32_bf16(w00, hA0, aA0, 0, 0, 0);
            aB0 = __builtin_amdgcn_mfma_f32_16x16x32_bf16(w00, hB0, aB0, 0, 0, 0);
            short8_t w10 = *(const short8_t*)(b0f + (size_t)((nt1 * 4 + 0) * 64 + lane) * 8);
            aA1 = __builtin_amdgcn_mfma_f32_16x16x32_bf16(w10, hA0, aA1, 0, 0, 0);
            aB1 = __builtin_amdgcn_mfma_f32_16x16x32_bf16(w10, hB0, aB1, 0, 0, 0);
            short8_t w01 = *(const short8_t*)(b0f + (size_t)((nt0 * 4 + 1) * 64 + lane) * 8);
            aA0 = __builtin_amdgcn_mfma_f32_16x16x32_bf16(w01, hA1, aA0, 0, 0, 0);
            aB0 = __builtin_amdgcn_mfma_f32_16x16x32_bf16(w01, hB1, aB0, 0, 0, 0);
            short8_t w11 = *(const short8_t*)(b0f + (size_t)((nt1 * 4 + 1) * 64 + lane) * 8);
            aA1 = __builtin_amdgcn_mfma_f32_16x16x32_bf16(w11, hA1, aA1, 0, 0, 0);
            aB1 = __builtin_amdgcn_mfma_f32_16x16x32_bf16(w11, hB1, aB1, 0, 0, 0);
            short8_t w02 = *(const short8_t*)(b0f + (size_t)((nt0 * 4 + 2) * 64 + lane) * 8);
            aA0 = __builtin_amdgcn_mfma_f32_16x16x32_bf16(w02, hA2, aA0, 0, 0, 0);
            aB0 = __builtin_amdgcn_mfma_f32_16x16x32_bf16(w02, hB2, aB0, 0, 0, 0);
            short8_t w12 = *(const short8_t*)(b0f + (size_t)((nt1 * 4 + 2) * 64 + lane) * 8);
            aA1 = __builtin_amdgcn_mfma_f32_16x16x32_bf16(w12, hA2, aA1, 0, 0, 0);
            aB1 = __builtin_amdgcn_mfma_f32_16x16x32_bf16(w12, hB2, aB1, 0, 0, 0);
            short8_t w03 = *(const short8_t*)(b0f + (size_t)((nt0 * 4 + 3) * 64 + lane) * 8);
            aA0 = __builtin_amdgcn_mfma_f32_16x16x32_bf16(w03, hA3, aA0, 0, 0, 0);
            aB0 = __builtin_amdgcn_mfma_f32_16x16x32_bf16(w03, hB3, aB0, 0, 0, 0);
            short8_t w13 = *(const short8_t*)(b0f + (size_t)((nt1 * 4 + 3) * 64 + lane) * 8);
            aA1 = __builtin_amdgcn_mfma_f32_16x16x32_bf16(w13, hA3, aA1, 0, 0, 0);
            aB1 = __builtin_amdgcn_mfma_f32_16x16x32_bf16(w13, hB3, aB1, 0, 0, 0);
        }
        int d0 = nt0 * 16 + g * 4;
        int d1 = d0 + 16;
        if (okA) {
            float4 g0 = *(const float4*)(ycA + d0);
            float4 g1 = *(const float4*)(ycA + d1);
            float4 r0, r1;
            r0.x = aA0[0] + g0.x; r0.y = aA0[1] + g0.y; r0.z = aA0[2] + g0.z; r0.w = aA0[3] + g0.w;
            r1.x = aA1[0] + g1.x; r1.y = aA1[1] + g1.y; r1.z = aA1[2] + g1.z; r1.w = aA1[3] + g1.w;
            *(float4*)(out + (size_t)pA * DD + d0) = r0;
            *(float4*)(out + (size_t)pA * DD + d1) = r1;
        }
        if (okB) {
            float4 g0 = *(const float4*)(ycB + d0);
            float4 g1 = *(const float4*)(ycB + d1);
            float4 r0, r1;
            r0.x = aB0[0] + g0.x; r0.y = aB0[1] + g0.y; r0.z = aB0[2] + g0.z; r0.w = aB0[3] + g0.w;
            r1.x = aB1[0] + g1.x; r1.y = aB1[1] + g1.y; r1.z = aB1[2] + g1.z; r1.w = aB1[3] + g1.w;
            *(float4*)(out + (size_t)pB * DD + d0) = r0;
            *(float4*)(out + (size_t)pB * DD + d1) = r1;
        }
    }
}

extern "C" void kernel_launch(void* const* d_in, const int* in_sizes, int n_in,
                              void* d_out, int out_size, void* d_ws, size_t ws_size,
                              hipStream_t stream) {
    (void)n_in; (void)out_size; (void)ws_size;
    const float* h   = (const float*)d_in[0];
    const int* inv0  = (const int*)d_in[2];
    const int* inv1  = (const int*)d_in[3];
    const int* inv2  = (const int*)d_in[4];
    const int* M0    = (const int*)d_in[5];
    const int* M1    = (const int*)d_in[6];
    const int* M2    = (const int*)d_in[7];
    const float* Wqkv = (const float*)d_in[8];
    const float* bqkv = (const float*)d_in[9];
    const float* Wo   = (const float*)d_in[10];
    const float* bo   = (const float*)d_in[11];
    const float* ln1s = (const float*)d_in[12];
    const float* ln1b = (const float*)d_in[13];
    const float* W1   = (const float*)d_in[14];
    const float* b1   = (const float*)d_in[15];
    const float* W2   = (const float*)d_in[16];
    const float* b2   = (const float*)d_in[17];
    const float* ln2s = (const float*)d_in[18];
    const float* ln2b = (const float*)d_in[19];
    const float* Wf   = (const float*)d_in[20];
    const float* bf   = (const float*)d_in[21];
    int N = in_sizes[0] / DD;

    float* ws      = (float*)d_ws;
    float* macro   = ws;                                    // NS*MC*DD
    float* counts  = macro + (size_t)NS * MC * DD;          // NS*MC
    float* qkvb    = counts + (size_t)NS * MC;              // NS*MC*3*DD
    float* attno   = qkvb + (size_t)NS * MC * 3 * DD;       // NS*MC*DD
    float* yb      = attno + (size_t)NS * MC * DD;          // NS*MC*DD
    float* b0f_f   = yb + (size_t)NS * MC * DD;             // DD*DD floats of space (b0f uses half)
    unsigned short* b0f = (unsigned short*)b0f_f;
    float* part_o  = b0f_f + (size_t)DD * DD;               // NS*NHH*64*NSPLIT*2048
    float* part_ml = part_o + (size_t)NS * NHH * 64 * NSPLIT * 2048;  // NS*NHH*64*NSPLIT*128
    float* ycb     = part_ml + (size_t)NS * NHH * 64 * NSPLIT * 128;  // MC*DD
    int* ip        = (int*)(ycb + (size_t)MC * DD);
    int* parent10  = ip;                // MC
    int* parent21  = parent10 + MC;     // 512
    int* cnt_i     = parent21 + 512;    // MC
    int* fill      = cnt_i + MC;        // MC
    int* offs      = fill + MC;         // MC
    int* order     = offs + MC;         // N

    float* sum0 = macro;
    float* sum1 = macro + (size_t)1 * MC * DD;
    float* sum2 = macro + (size_t)2 * MC * DD;
    float* cnt0 = counts;
    float* cnt1 = counts + MC;
    float* cnt2 = counts + 2 * MC;

    hipMemsetAsync(macro, 0, ((size_t)NS * MC * DD + NS * MC) * sizeof(float), stream);
    hipMemsetAsync(cnt_i, 0, (size_t)2 * MC * sizeof(int), stream);

    int nb = (N + 255) / 256;
    k_parent<<<nb, 256, 0, stream>>>(inv0, inv1, inv2, parent10, parent21, cnt_i, N);
    k_scan<<<1, 1024, 0, stream>>>(cnt_i, offs);
    k_place<<<nb, 256, 0, stream>>>(inv0, offs, fill, order, N);
    k_pool<<<MC, 256, 0, stream>>>(h, order, offs, cnt_i, sum0, cnt0, M0);
    k_rollup<<<(MC * DD) / 256, 256, 0, stream>>>(sum0, cnt0, parent10, sum1, cnt1, M0, MC);
    k_rollup<<<(512 * DD) / 256, 256, 0, stream>>>(sum1, cnt1, parent21, sum2, cnt2, M1, 512);
    k_finalize<<<(NS * MC * DD) / 256, 256, 0, stream>>>(macro, counts, M0, M1, M2);
    k_b0frag<<<64, 256, 0, stream>>>(Wf, b0f);
    k_qkv<<<dim3(MC / 8, NS), 256, 0, stream>>>(macro, Wqkv, bqkv, qkvb, M0, M1, M2);
    k_attn_part<<<dim3(MC / 64, NHH, NS * NSPLIT), 256, 0, stream>>>(qkvb, part_o, part_ml, M0, M1, M2);
    k_attn_comb<<<dim3(MC / 64, NHH, NS), 256, 0, stream>>>(part_o, part_ml, attno, M0, M1, M2);
    k_layer<<<dim3(MC / 8, NS), 256, 0, stream>>>(macro, attno, Wo, bo, ln1s, ln1b,
                                                  W1, b1, W2, b2, ln2s, ln2b, Wf, yb, M0, M1, M2);
    k_ycomb<<<(MC * DD) / 256, 256, 0, stream>>>(yb, parent10, parent21, bf, ycb, M0);
    int ntasks = (N + 15) >> 4;
    int npairs = (ntasks + 1) / 2;
    k_final<<<(npairs + 3) / 4, 256, 0, stream>>>(h, b0f, ycb, inv0, (float*)d_out, N);
}